// Round 10
// baseline (236.914 us; speedup 1.0000x reference)
//
#include <hip/hip_runtime.h>
#include <math.h>

static constexpr int B = 32, C = 256, HW = 4096, CS = 16;
static constexpr int BHW = B * HW;                 // 131072
static constexpr size_t IMG = (size_t)B * CS * HW; // 2,097,152 floats per branch buffer

// ---------- workspace layout (floats) ----------
static constexpr size_t OFF_S    = 0;        // 8 ops x 512 (b*16+k) per-(b,c) sums
static constexpr size_t OFF_SQ   = 4096;     // 8 ops x 512 sumsq
static constexpr size_t OFF_U    = 8192;     // u3sum[16],u3sq[16],u5sum[16],u5sq[16]
static constexpr size_t OFF_CNT  = 8256;     // 2 uint counters (sesel, fuseD)
static constexpr size_t ACC_END  = 8260;     // zero region [0, ACC_END) zeroed by k_stats blk0
static constexpr size_t OFF_MX   = 8320;
static constexpr size_t OFF_AV   = OFF_MX + 8192;
static constexpr size_t OFF_NUM  = OFF_AV + 8192;
static constexpr size_t OFF_Y    = OFF_NUM + 8192;    // B*128
static constexpr size_t OFF_ACO  = OFF_Y + 4096;      // B*16*8
static constexpr size_t OFF_BIAS = OFF_ACO + 4096;    // B*16
static constexpr size_t OFF_INT  = OFF_BIAS + 512;    // idx[16], selmap[256] as ints
static constexpr size_t OFF_R    = OFF_INT + 384;     // 6 x IMG floats

__device__ inline float wave_sum(float v) {
  v += __shfl_down(v, 32); v += __shfl_down(v, 16); v += __shfl_down(v, 8);
  v += __shfl_down(v, 4);  v += __shfl_down(v, 2);  v += __shfl_down(v, 1);
  return v;
}
__device__ inline float wave_max(float v) {
  v = fmaxf(v, __shfl_down(v, 32)); v = fmaxf(v, __shfl_down(v, 16));
  v = fmaxf(v, __shfl_down(v, 8));  v = fmaxf(v, __shfl_down(v, 4));
  v = fmaxf(v, __shfl_down(v, 2));  v = fmaxf(v, __shfl_down(v, 1));
  return v;
}

// ---- K1: per-(b,c) max/mean over HxW; block 0 also zeroes the accumulator region ----
__global__ __launch_bounds__(256) void k_stats(const float4* __restrict__ x,
                                               float* __restrict__ mx, float* __restrict__ av,
                                               float* __restrict__ accbase) {
  int bc = blockIdx.x;
  if (bc == 0) for (int i = threadIdx.x; i < (int)ACC_END; i += 256) accbase[i] = 0.f;
  const float4* p = x + (size_t)bc * 1024;
  float mmax = -INFINITY, msum = 0.f;
  for (int i = threadIdx.x; i < 1024; i += 256) {
    float4 v = p[i];
    mmax = fmaxf(mmax, fmaxf(fmaxf(v.x, v.y), fmaxf(v.z, v.w)));
    msum += v.x + v.y + v.z + v.w;
  }
  __shared__ float rs[4], rm[4];
  float s = wave_sum(msum), m = wave_max(mmax);
  int w = threadIdx.x >> 6;
  if ((threadIdx.x & 63) == 0) { rs[w] = s; rm[w] = m; }
  __syncthreads();
  if (threadIdx.x == 0) {
    mx[bc] = fmaxf(fmaxf(rm[0], rm[1]), fmaxf(rm[2], rm[3]));
    av[bc] = (rs[0] + rs[1] + rs[2] + rs[3]) * (1.f / 4096.f);
  }
}

// ---- K2: SE -> num, with last-block tail doing the top-16 select ----
__global__ __launch_bounds__(256) void k_sesel(const float* __restrict__ mx, const float* __restrict__ av,
                                               const float* __restrict__ w1, const float* __restrict__ w2,
                                               float* __restrict__ num,
                                               int* __restrict__ idx, int* __restrict__ selmap,
                                               unsigned* __restrict__ cnt) {
  __shared__ float zs0[256], zs1[256], h0[128], h1[128];
  __shared__ unsigned lastv;
  int b = blockIdx.x, t = threadIdx.x;
  zs0[t] = mx[b * 256 + t]; zs1[t] = av[b * 256 + t];
  __syncthreads();
  if (t < 128) {
    const float* wr = w1 + (size_t)t * 256;
    float am = 0.f, aa = 0.f;
    for (int i = 0; i < 256; i++) { float w = wr[i]; am = fmaf(w, zs0[i], am); aa = fmaf(w, zs1[i], aa); }
    h0[t] = fmaxf(am, 0.f); h1[t] = fmaxf(aa, 0.f);
  }
  __syncthreads();
  {
    const float* wr = w2 + (size_t)t * 128;
    float sm = 0.f, sa = 0.f;
    for (int j = 0; j < 128; j++) { float w = wr[j]; sm = fmaf(w, h0[j], sm); sa = fmaf(w, h1[j], sa); }
    num[b * 256 + t] = 1.f / (1.f + expf(-(sm + sa)));
  }
  __threadfence();
  if (t == 0) lastv = atomicAdd(cnt, 1u);
  __syncthreads();
  if (lastv == 31u) {
    __threadfence();
    float acc = 0.f;
    for (int bb = 0; bb < B; bb++) acc += num[bb * 256 + t];
    zs0[t] = acc; selmap[t] = -1;
    __syncthreads();
    float v = zs0[t];
    int rank = 0;
    for (int c = 0; c < 256; c++) {
      float o = zs0[c];
      rank += (o > v) || (o == v && c < t);
    }
    if (rank < 16) { idx[rank] = t; selmap[t] = rank; }
  }
}

// ---- Phase A: (b,k,quarter). Stage gated channel quarter (24x72, pad 4); write pools
// + stats + identity sum + all four first-stage dw convs. ----
__global__ __launch_bounds__(256) void k_fuseA(
    const float* __restrict__ x, const float* __restrict__ num, const int* __restrict__ idx,
    const float* __restrict__ d3dw, const float* __restrict__ d5dw,
    const float* __restrict__ s3dw1, const float* __restrict__ s5dw1,
    float* __restrict__ scr, float* __restrict__ R,
    float* __restrict__ S, float* __restrict__ SQ) {
  __shared__ float lt[24 * 72];
  __shared__ float red[20];
  const int t = threadIdx.x;
  const int blk = blockIdx.x;            // 2048 = 512 bk x 4 quarters
  const int bk = blk >> 2, qt = blk & 3;
  const int b = bk >> 4, k = bk & 15;
  const int c = idx[k];
  const float sc = num[b * 256 + c];
  const float* src = x + ((size_t)b * 256 + c) * HW;
  const size_t o = (size_t)bk * HW + qt * 1024;
  const int ry0 = qt * 16;
  for (int i = t; i < 24 * 72; i += 256) {
    int ty = i / 72, tx = i - ty * 72;
    int y = ry0 - 4 + ty, xx = tx - 4;
    float v = 0.f;
    if ((unsigned)y < 64u && (unsigned)xx < 64u) v = src[y * 64 + xx] * sc;
    lt[i] = v;
  }
  __syncthreads();
  // pools + identity sum + stats (atomic per-(b,k))
  {
    float s1 = 0.f, q1 = 0.f, s2 = 0.f, q2 = 0.f, s3 = 0.f;
    for (int i = t; i < 1024; i += 256) {
      int lr = i >> 6, col = i & 63;
      int y = ry0 + lr;
      const float* ctr = lt + (lr + 4) * 72 + (col + 4);
      int dy0 = (y > 0) ? -1 : 0, dy1 = (y < 63) ? 1 : 0;
      int dx0 = (col > 0) ? -1 : 0, dx1 = (col < 63) ? 1 : 0;
      float mxv = -INFINITY, sm = 0.f;
      for (int dy = dy0; dy <= dy1; dy++)
        for (int dx = dx0; dx <= dx1; dx++) { float v = ctr[dy * 72 + dx]; mxv = fmaxf(mxv, v); sm += v; }
      float avv = sm / (float)((dy1 - dy0 + 1) * (dx1 - dx0 + 1));
      R[o + i] = mxv; R[IMG + o + i] = avv;
      s1 += mxv; q1 += mxv * mxv; s2 += avv; q2 += avv * avv; s3 += ctr[0];
    }
    s1 = wave_sum(s1); q1 = wave_sum(q1); s2 = wave_sum(s2); q2 = wave_sum(q2); s3 = wave_sum(s3);
    int w = t >> 6;
    if ((t & 63) == 0) { red[w] = s1; red[4 + w] = q1; red[8 + w] = s2; red[12 + w] = q2; red[16 + w] = s3; }
    __syncthreads();
    if (t == 0) {
      atomicAdd(&S[512 + bk],   red[0] + red[1] + red[2] + red[3]);
      atomicAdd(&SQ[512 + bk],  red[4] + red[5] + red[6] + red[7]);
      atomicAdd(&S[1024 + bk],  red[8] + red[9] + red[10] + red[11]);
      atomicAdd(&SQ[1024 + bk], red[12] + red[13] + red[14] + red[15]);
      atomicAdd(&S[1536 + bk],  red[16] + red[17] + red[18] + red[19]);
    }
  }
  // dil3 (K3, dil2)
  {
    float w[9];
#pragma unroll
    for (int i = 0; i < 9; i++) w[i] = d3dw[k * 9 + i];
    for (int i = t; i < 1024; i += 256) {
      int lr = i >> 6, col = i & 63;
      const float* ctr = lt + (lr + 4) * 72 + (col + 4);
      float acc = 0.f;
#pragma unroll
      for (int a = 0; a < 3; a++)
#pragma unroll
        for (int q = 0; q < 3; q++)
          acc = fmaf(w[a * 3 + q], fmaxf(ctr[(2 * a - 2) * 72 + (2 * q - 2)], 0.f), acc);
      scr[0 * IMG + o + i] = acc;
    }
  }
  // dil5 (K5, dil2)
  {
    float w[25];
#pragma unroll
    for (int i = 0; i < 25; i++) w[i] = d5dw[k * 25 + i];
    for (int i = t; i < 1024; i += 256) {
      int lr = i >> 6, col = i & 63;
      const float* ctr = lt + (lr + 4) * 72 + (col + 4);
      float acc = 0.f;
#pragma unroll
      for (int a = 0; a < 5; a++)
#pragma unroll
        for (int q = 0; q < 5; q++)
          acc = fmaf(w[a * 5 + q], fmaxf(ctr[(2 * a - 4) * 72 + (2 * q - 4)], 0.f), acc);
      scr[1 * IMG + o + i] = acc;
    }
  }
  // sep3 stage-1 dw
  {
    float w[9];
#pragma unroll
    for (int i = 0; i < 9; i++) w[i] = s3dw1[k * 9 + i];
    for (int i = t; i < 1024; i += 256) {
      int lr = i >> 6, col = i & 63;
      const float* ctr = lt + (lr + 4) * 72 + (col + 4);
      float acc = 0.f;
#pragma unroll
      for (int a = 0; a < 3; a++)
#pragma unroll
        for (int q = 0; q < 3; q++)
          acc = fmaf(w[a * 3 + q], fmaxf(ctr[(a - 1) * 72 + (q - 1)], 0.f), acc);
      scr[2 * IMG + o + i] = acc;
    }
  }
  // sep5 stage-1 dw
  {
    float w[25];
#pragma unroll
    for (int i = 0; i < 25; i++) w[i] = s5dw1[k * 25 + i];
    for (int i = t; i < 1024; i += 256) {
      int lr = i >> 6, col = i & 63;
      const float* ctr = lt + (lr + 4) * 72 + (col + 4);
      float acc = 0.f;
#pragma unroll
      for (int a = 0; a < 5; a++)
#pragma unroll
        for (int q = 0; q < 5; q++)
          acc = fmaf(w[a * 5 + q], fmaxf(ctr[(a - 2) * 72 + (q - 2)], 0.f), acc);
      scr[3 * IMG + o + i] = acc;
    }
  }
}

// ---- pointwise 16x16 helper: 4 px/thread via float4, stats amortized ----
__device__ __forceinline__ void pw4(const float* __restrict__ in, const float* __restrict__ w16,
                                    float* __restrict__ out, float* __restrict__ sacc,
                                    float* __restrict__ qacc, int perB, int b, int q4,
                                    float* wsh, float* redS, float* redQ) {
  int t = threadIdx.x;
  wsh[t] = w16[t];
  size_t base = (size_t)b * 16 * HW + q4 * 1024 + t * 4;
  float4 sv[16];
#pragma unroll
  for (int i = 0; i < 16; i++) sv[i] = *(const float4*)(in + base + (size_t)i * HW);
  __syncthreads();
  int wv = t >> 6, lane = t & 63;
#pragma unroll
  for (int cc = 0; cc < 16; cc++) {
    float4 o; o.x = 0.f; o.y = 0.f; o.z = 0.f; o.w = 0.f;
#pragma unroll
    for (int i = 0; i < 16; i++) {
      float w = wsh[cc * 16 + i];
      o.x = fmaf(w, sv[i].x, o.x); o.y = fmaf(w, sv[i].y, o.y);
      o.z = fmaf(w, sv[i].z, o.z); o.w = fmaf(w, sv[i].w, o.w);
    }
    *(float4*)(out + base + (size_t)cc * HW) = o;
    float s = (o.x + o.y) + (o.z + o.w);
    float qv = fmaf(o.x, o.x, fmaf(o.y, o.y, fmaf(o.z, o.z, o.w * o.w)));
    s = wave_sum(s); qv = wave_sum(qv);
    if (lane == 0) { redS[cc * 4 + wv] = s; redQ[cc * 4 + wv] = qv; }
  }
  __syncthreads();
  if (t < 16) {
    float s = redS[t * 4] + redS[t * 4 + 1] + redS[t * 4 + 2] + redS[t * 4 + 3];
    float q = redQ[t * 4] + redQ[t * 4 + 1] + redQ[t * 4 + 2] + redQ[t * 4 + 3];
    int sl = perB ? b * 16 + t : t;
    atomicAdd(&sacc[sl], s); atomicAdd(&qacc[sl], q);
  }
}

// ---- Phase B: 4 first pointwise convs, one op per block (512 blocks) ----
__global__ __launch_bounds__(256) void k_fuseB(
    const float* __restrict__ scr,
    const float* __restrict__ d3pw, const float* __restrict__ d5pw,
    const float* __restrict__ s3pw1, const float* __restrict__ s5pw1,
    float* __restrict__ R, float* __restrict__ t3, float* __restrict__ t5,
    float* __restrict__ S, float* __restrict__ SQ, float* __restrict__ U) {
  __shared__ float wsh[256], redS[64], redQ[64];
  int blk = blockIdx.x;
  int op = blk >> 7, rem = blk & 127;
  int b = rem >> 2, q4 = rem & 3;
  switch (op) {
    case 0: pw4(scr + 0 * IMG, d3pw,  R + 4 * IMG, S + 6 * 512, SQ + 6 * 512, 1, b, q4, wsh, redS, redQ); break;
    case 1: pw4(scr + 1 * IMG, d5pw,  R + 5 * IMG, S + 7 * 512, SQ + 7 * 512, 1, b, q4, wsh, redS, redQ); break;
    case 2: pw4(scr + 2 * IMG, s3pw1, t3, U + 0,  U + 16, 0, b, q4, wsh, redS, redQ); break;
    case 3: pw4(scr + 3 * IMG, s5pw1, t5, U + 32, U + 48, 0, b, q4, wsh, redS, redQ); break;
  }
}

// ---- Phase C: second dw convs with lazy-bn, one (op,b,k,quarter) per block ----
template<int KK>
__device__ __forceinline__ void dw_q(const float* __restrict__ src, const float* __restrict__ w,
                                     float* __restrict__ dst, float* lt, float mu, float rs, int qt) {
  constexpr int P = KK / 2, TW = 64 + 2 * P, ROWS = 16 + 2 * P;
  float wr[KK * KK];
#pragma unroll
  for (int i = 0; i < KK * KK; i++) wr[i] = w[i];
  const int t = threadIdx.x;
  const int ry0 = qt * 16;
  for (int i = t; i < ROWS * TW; i += 256) {
    int ty = i / TW, tx = i - ty * TW;
    int y = ry0 - P + ty, xx = tx - P;
    float v = 0.f;
    if ((unsigned)y < 64u && (unsigned)xx < 64u) {
      v = src[y * 64 + xx];
      v = (v - mu) * rs;
      v = fmaxf(v, 0.f);
    }
    lt[i] = v;
  }
  __syncthreads();
  for (int i = t; i < 1024; i += 256) {
    int lr = i >> 6, col = i & 63;
    const float* t0 = lt + lr * TW + col;
    float acc = 0.f;
#pragma unroll
    for (int a = 0; a < KK; a++)
#pragma unroll
      for (int q = 0; q < KK; q++)
        acc = fmaf(wr[a * KK + q], t0[a * TW + q], acc);
    dst[qt * 1024 + i] = acc;
  }
}

__global__ __launch_bounds__(256) void k_fuseC(
    const float* __restrict__ t3, const float* __restrict__ t5,
    const float* __restrict__ s3dw2, const float* __restrict__ s5dw2,
    float* __restrict__ scr, const float* __restrict__ U) {
  __shared__ float lt[20 * 68];
  int blk = blockIdx.x;                  // 4096 = 2 ops x 512 bk x 4 quarters
  int op = blk >> 11, rem = blk & 2047;
  int bk = rem >> 2, qt = rem & 3, k = bk & 15;
  size_t o = (size_t)bk * HW;
  if (op == 0) {
    float mu = U[k] * (1.f / (float)BHW);
    float var = U[16 + k] * (1.f / (float)BHW) - mu * mu;
    dw_q<3>(t3 + o, s3dw2 + k * 9, scr + 0 * IMG + o, lt, mu, rsqrtf(var + 1e-5f), qt);
  } else {
    float mu = U[32 + k] * (1.f / (float)BHW);
    float var = U[48 + k] * (1.f / (float)BHW) - mu * mu;
    dw_q<5>(t5 + o, s5dw2 + k * 25, scr + 1 * IMG + o, lt, mu, rsqrtf(var + 1e-5f), qt);
  }
}

// ---- Phase D: final pointwise convs (256 blocks) + last-block attention-MLP tail ----
__global__ __launch_bounds__(256) void k_fuseD(
    const float* __restrict__ scr,
    const float* __restrict__ s3pw2, const float* __restrict__ s5pw2,
    float* __restrict__ R, float* __restrict__ S, float* __restrict__ SQ,
    const float* __restrict__ w1, const float* __restrict__ w2,
    float* __restrict__ ybuf, float* __restrict__ aco, float* __restrict__ bia,
    unsigned* __restrict__ cnt) {
  __shared__ float wsh[256], redS[64], redQ[64];
  __shared__ unsigned lastv;
  int blk = blockIdx.x;
  int op = blk >> 7, rem = blk & 127;
  int b = rem >> 2, q4 = rem & 3;
  if (op == 0) pw4(scr + 0 * IMG, s3pw2, R + 2 * IMG, S + 4 * 512, SQ + 4 * 512, 1, b, q4, wsh, redS, redQ);
  else         pw4(scr + 1 * IMG, s5pw2, R + 3 * IMG, S + 5 * 512, SQ + 5 * 512, 1, b, q4, wsh, redS, redQ);
  int t = threadIdx.x;
  __threadfence();
  __syncthreads();
  if (t == 0) lastv = atomicAdd(cnt, 1u);
  __syncthreads();
  if (lastv != 255u) return;
  __threadfence();
  // ---- attention MLP for all 32 batches, 16 at a time ----
  __shared__ float msh[128], rssh[128], ym2[16][129], hh2[16][17], ysh2[16][129];
  if (t < 128) {
    int op2 = t >> 4, k = t & 15;
    bool isbn = (op2 == 1 || op2 == 2 || op2 >= 4);
    float ss = 0.f, qq = 0.f;
    for (int bb = 0; bb < B; bb++) { ss += S[op2 * 512 + bb * 16 + k]; qq += SQ[op2 * 512 + bb * 16 + k]; }
    float m = 0.f, rsc = 0.f;
    if (isbn) { m = ss * (1.f / (float)BHW); float var = qq * (1.f / (float)BHW) - m * m; rsc = rsqrtf(var + 1e-5f); }
    msh[t] = m; rssh[t] = rsc;
  }
  __syncthreads();
  for (int half = 0; half < 2; half++) {
    int b0 = half * 16;
    for (int e = t; e < 2048; e += 256) {
      int bb = e >> 7, cc = e & 127, op2 = cc >> 4;
      float sm = S[op2 * 512 + (b0 + bb) * 16 + (cc & 15)] * (1.f / 4096.f);
      ym2[bb][cc] = (op2 == 0) ? 0.f : ((op2 == 3) ? sm : (sm - msh[cc]) * rssh[cc]);
    }
    __syncthreads();
    {
      int bb = t >> 4, u = t & 15;
      const float* wr = w1 + (size_t)u * 128;
      float acc = 0.f;
      for (int c2 = 0; c2 < 128; c2++) acc = fmaf(wr[c2], ym2[bb][c2], acc);
      hh2[bb][u] = fmaxf(acc, 0.f);
    }
    __syncthreads();
    for (int e = t; e < 2048; e += 256) {
      int bb = e >> 7, oo = e & 127;
      const float* wr = w2 + (size_t)oo * 16;
      float acc = 0.f;
      for (int j = 0; j < 16; j++) acc = fmaf(wr[j], hh2[bb][j], acc);
      float yy = 1.f / (1.f + expf(-acc));
      ysh2[bb][oo] = yy; ybuf[(b0 + bb) * 128 + oo] = yy;
    }
    __syncthreads();
    {
      int bb = t >> 4, kk = t & 15;
      float bias = 0.f;
      for (int o2 = 1; o2 < 8; o2++) {
        float yv = ysh2[bb][o2 * 16 + kk];
        float a;
        if (o2 == 3) a = yv;
        else { a = yv * rssh[o2 * 16 + kk]; bias -= a * msh[o2 * 16 + kk]; }
        aco[((b0 + bb) * 16 + kk) * 8 + o2] = a;
      }
      bia[(b0 + bb) * 16 + kk] = bias;
    }
    __syncthreads();
  }
}

// ---- final fused write: fully vectorized; identity folded into x coefficient ----
__global__ __launch_bounds__(256) void k_final(const float* __restrict__ x, const float* __restrict__ num,
                                               const int* __restrict__ selmap,
                                               const float* __restrict__ rbuf, const float* __restrict__ aco,
                                               const float* __restrict__ bia, const float* __restrict__ ybuf,
                                               float* __restrict__ out, float* __restrict__ out8) {
  __shared__ float sh[256];
  int bc = blockIdx.x;
  if (bc == B * C) {
    int t = threadIdx.x, op = t >> 5, lane = t & 31;
    float acc = 0.f;
    for (int i = lane; i < 512; i += 32) { int bb = i >> 4, kk = i & 15; acc += ybuf[bb * 128 + op * 16 + kk]; }
    sh[t] = acc;
    __syncthreads();
    if (lane == 0) {
      float s = 0.f;
      for (int i = 0; i < 32; i++) s += sh[op * 32 + i];
      out8[op] = s;
    }
    return;
  }
  int b = bc >> 8;
  int k = selmap[bc & 255];
  const float4* xs = (const float4*)(x + (size_t)bc * HW);
  float4* od = (float4*)(out + (size_t)bc * HW);
  if (k < 0) {
    float sc = 1.f + num[bc];
    for (int i = threadIdx.x; i < 1024; i += 256) {
      float4 v = xs[i];
      v.x *= sc; v.y *= sc; v.z *= sc; v.w *= sc;
      od[i] = v;
    }
  } else {
    int bk = b * 16 + k;
    float scn = num[bc];                 // idx[k] == own channel: identity = x*scn, folded into xc
    const float4* r0 = (const float4*)(rbuf + ((size_t)0 * 512 + bk) * HW);
    const float4* r1 = (const float4*)(rbuf + ((size_t)1 * 512 + bk) * HW);
    const float4* r2 = (const float4*)(rbuf + ((size_t)2 * 512 + bk) * HW);
    const float4* r3 = (const float4*)(rbuf + ((size_t)3 * 512 + bk) * HW);
    const float4* r4 = (const float4*)(rbuf + ((size_t)4 * 512 + bk) * HW);
    const float4* r5 = (const float4*)(rbuf + ((size_t)5 * 512 + bk) * HW);
    float a1 = aco[bk * 8 + 1], a2 = aco[bk * 8 + 2];
    float a4 = aco[bk * 8 + 4], a5 = aco[bk * 8 + 5], a6 = aco[bk * 8 + 6], a7 = aco[bk * 8 + 7];
    float xc = 1.f + aco[bk * 8 + 3] * scn;
    float bias = bia[bk];
    for (int i = threadIdx.x; i < 1024; i += 256) {
      float4 xv = xs[i];
      float4 v0 = r0[i], v1 = r1[i], v2 = r2[i], v3 = r3[i], v4 = r4[i], v5 = r5[i];
      float4 o;
      o.x = xv.x * xc + bias + a1 * v0.x + a2 * v1.x + a4 * v2.x + a5 * v3.x + a6 * v4.x + a7 * v5.x;
      o.y = xv.y * xc + bias + a1 * v0.y + a2 * v1.y + a4 * v2.y + a5 * v3.y + a6 * v4.y + a7 * v5.y;
      o.z = xv.z * xc + bias + a1 * v0.z + a2 * v1.z + a4 * v2.z + a5 * v3.z + a6 * v4.z + a7 * v5.z;
      o.w = xv.w * xc + bias + a1 * v0.w + a2 * v1.w + a4 * v2.w + a5 * v3.w + a6 * v4.w + a7 * v5.w;
      od[i] = o;
    }
  }
}

extern "C" void kernel_launch(void* const* d_in, const int* in_sizes, int n_in,
                              void* d_out, int out_size, void* d_ws, size_t ws_size,
                              hipStream_t stream) {
  const float* x      = (const float*)d_in[0];
  const float* ca_w1  = (const float*)d_in[1];
  const float* ca_w2  = (const float*)d_in[2];
  const float* s3_dw1 = (const float*)d_in[3];
  const float* s3_pw1 = (const float*)d_in[4];
  const float* s3_dw2 = (const float*)d_in[5];
  const float* s3_pw2 = (const float*)d_in[6];
  const float* s5_dw1 = (const float*)d_in[7];
  const float* s5_pw1 = (const float*)d_in[8];
  const float* s5_dw2 = (const float*)d_in[9];
  const float* s5_pw2 = (const float*)d_in[10];
  const float* d3_dw  = (const float*)d_in[11];
  const float* d3_pw  = (const float*)d_in[12];
  const float* d5_dw  = (const float*)d_in[13];
  const float* d5_pw  = (const float*)d_in[14];
  const float* at_w1  = (const float*)d_in[15];
  const float* at_w2  = (const float*)d_in[16];

  float* ws = (float*)d_ws;
  float* S = ws + OFF_S;  float* SQ = ws + OFF_SQ;  float* U = ws + OFF_U;
  unsigned* cnt = (unsigned*)(ws + OFF_CNT);
  float* mx = ws + OFF_MX; float* av = ws + OFF_AV; float* num = ws + OFF_NUM;
  float* ybuf = ws + OFF_Y; float* aco = ws + OFF_ACO; float* bia = ws + OFF_BIAS;
  int* ib = (int*)(ws + OFF_INT);
  int* idx = ib; int* selmap = ib + 16;
  float* R = ws + OFF_R;

  float* outf = (float*)d_out;
  float* scr = outf;             // 4 x IMG scratch inside d_out (dead before k_final)
  float* t3  = outf + 4 * IMG;
  float* t5  = outf + 5 * IMG;
  float* out8 = outf + (size_t)B * C * HW;

  k_stats<<<B * C, 256, 0, stream>>>((const float4*)x, mx, av, ws);
  k_sesel<<<B, 256, 0, stream>>>(mx, av, ca_w1, ca_w2, num, idx, selmap, cnt);
  k_fuseA<<<2048, 256, 0, stream>>>(x, num, idx, d3_dw, d5_dw, s3_dw1, s5_dw1, scr, R, S, SQ);
  k_fuseB<<<512, 256, 0, stream>>>(scr, d3_pw, d5_pw, s3_pw1, s5_pw1, R, t3, t5, S, SQ, U);
  k_fuseC<<<4096, 256, 0, stream>>>(t3, t5, s3_dw2, s5_dw2, scr, U);
  k_fuseD<<<256, 256, 0, stream>>>(scr, s3_pw2, s5_pw2, R, S, SQ, at_w1, at_w2, ybuf, aco, bia, cnt + 1);
  k_final<<<B * C + 1, 256, 0, stream>>>(x, num, selmap, R, aco, bia, ybuf, outf, out8);
}

// Round 11
// 202.093 us; speedup vs baseline: 1.1723x; 1.1723x over previous
//
#include <hip/hip_runtime.h>
#include <math.h>

static constexpr int B = 32, C = 256, HW = 4096, CS = 16;
static constexpr int BHW = B * HW;                 // 131072
static constexpr size_t IMG = (size_t)B * CS * HW; // 2,097,152 floats per branch buffer

// ---------- workspace layout (floats) ----------
static constexpr size_t OFF_S    = 0;        // 8 ops x 512 (b*16+k) per-(b,c) sums
static constexpr size_t OFF_SQ   = 4096;     // 8 ops x 512 sumsq
static constexpr size_t OFF_U    = 8192;     // u3sum[16],u3sq[16],u5sum[16],u5sq[16]
static constexpr size_t OFF_CNT  = 8256;     // uint counter (sesel)
static constexpr size_t ACC_END  = 8260;     // zero region [0, ACC_END) zeroed by k_stats blk0
static constexpr size_t OFF_MX   = 8320;
static constexpr size_t OFF_AV   = OFF_MX + 8192;
static constexpr size_t OFF_NUM  = OFF_AV + 8192;
static constexpr size_t OFF_Y    = OFF_NUM + 8192;    // B*128
static constexpr size_t OFF_ACO  = OFF_Y + 4096;      // B*16*8
static constexpr size_t OFF_BIAS = OFF_ACO + 4096;    // B*16
static constexpr size_t OFF_INT  = OFF_BIAS + 512;    // idx[16], selmap[256] as ints
static constexpr size_t OFF_R    = OFF_INT + 384;     // 6 x IMG floats

__device__ inline float wave_sum(float v) {
  v += __shfl_down(v, 32); v += __shfl_down(v, 16); v += __shfl_down(v, 8);
  v += __shfl_down(v, 4);  v += __shfl_down(v, 2);  v += __shfl_down(v, 1);
  return v;
}
__device__ inline float wave_max(float v) {
  v = fmaxf(v, __shfl_down(v, 32)); v = fmaxf(v, __shfl_down(v, 16));
  v = fmaxf(v, __shfl_down(v, 8));  v = fmaxf(v, __shfl_down(v, 4));
  v = fmaxf(v, __shfl_down(v, 2));  v = fmaxf(v, __shfl_down(v, 1));
  return v;
}

// ---- K1: per-(b,c) max/mean over HxW; block 0 also zeroes the accumulator region ----
__global__ __launch_bounds__(256) void k_stats(const float4* __restrict__ x,
                                               float* __restrict__ mx, float* __restrict__ av,
                                               float* __restrict__ accbase) {
  int bc = blockIdx.x;
  if (bc == 0) for (int i = threadIdx.x; i < (int)ACC_END; i += 256) accbase[i] = 0.f;
  const float4* p = x + (size_t)bc * 1024;
  float mmax = -INFINITY, msum = 0.f;
  for (int i = threadIdx.x; i < 1024; i += 256) {
    float4 v = p[i];
    mmax = fmaxf(mmax, fmaxf(fmaxf(v.x, v.y), fmaxf(v.z, v.w)));
    msum += v.x + v.y + v.z + v.w;
  }
  __shared__ float rs[4], rm[4];
  float s = wave_sum(msum), m = wave_max(mmax);
  int w = threadIdx.x >> 6;
  if ((threadIdx.x & 63) == 0) { rs[w] = s; rm[w] = m; }
  __syncthreads();
  if (threadIdx.x == 0) {
    mx[bc] = fmaxf(fmaxf(rm[0], rm[1]), fmaxf(rm[2], rm[3]));
    av[bc] = (rs[0] + rs[1] + rs[2] + rs[3]) * (1.f / 4096.f);
  }
}

// ---- K2: SE -> num, with last-block tail doing the top-16 select ----
__global__ __launch_bounds__(256) void k_sesel(const float* __restrict__ mx, const float* __restrict__ av,
                                               const float* __restrict__ w1, const float* __restrict__ w2,
                                               float* __restrict__ num,
                                               int* __restrict__ idx, int* __restrict__ selmap,
                                               unsigned* __restrict__ cnt) {
  __shared__ float zs0[256], zs1[256], h0[128], h1[128];
  __shared__ unsigned lastv;
  int b = blockIdx.x, t = threadIdx.x;
  zs0[t] = mx[b * 256 + t]; zs1[t] = av[b * 256 + t];
  __syncthreads();
  if (t < 128) {
    const float* wr = w1 + (size_t)t * 256;
    float am = 0.f, aa = 0.f;
    for (int i = 0; i < 256; i++) { float w = wr[i]; am = fmaf(w, zs0[i], am); aa = fmaf(w, zs1[i], aa); }
    h0[t] = fmaxf(am, 0.f); h1[t] = fmaxf(aa, 0.f);
  }
  __syncthreads();
  {
    const float* wr = w2 + (size_t)t * 128;
    float sm = 0.f, sa = 0.f;
    for (int j = 0; j < 128; j++) { float w = wr[j]; sm = fmaf(w, h0[j], sm); sa = fmaf(w, h1[j], sa); }
    num[b * 256 + t] = 1.f / (1.f + expf(-(sm + sa)));
  }
  __threadfence();
  if (t == 0) lastv = atomicAdd(cnt, 1u);
  __syncthreads();
  if (lastv == 31u) {
    __threadfence();
    float acc = 0.f;
    for (int bb = 0; bb < B; bb++) acc += num[bb * 256 + t];
    zs0[t] = acc; selmap[t] = -1;
    __syncthreads();
    float v = zs0[t];
    int rank = 0;
    for (int c = 0; c < 256; c++) {
      float o = zs0[c];
      rank += (o > v) || (o == v && c < t);
    }
    if (rank < 16) { idx[rank] = t; selmap[t] = rank; }
  }
}

// ---- Phase A: (b,k,quarter). Stage gated channel quarter (24x72, pad 4); write pools
// + stats + identity sum + all four first-stage dw convs. ----
__global__ __launch_bounds__(256) void k_fuseA(
    const float* __restrict__ x, const float* __restrict__ num, const int* __restrict__ idx,
    const float* __restrict__ d3dw, const float* __restrict__ d5dw,
    const float* __restrict__ s3dw1, const float* __restrict__ s5dw1,
    float* __restrict__ scr, float* __restrict__ R,
    float* __restrict__ S, float* __restrict__ SQ) {
  __shared__ float lt[24 * 72];
  __shared__ float red[20];
  const int t = threadIdx.x;
  const int blk = blockIdx.x;            // 2048 = 512 bk x 4 quarters
  const int bk = blk >> 2, qt = blk & 3;
  const int b = bk >> 4, k = bk & 15;
  const int c = idx[k];
  const float sc = num[b * 256 + c];
  const float* src = x + ((size_t)b * 256 + c) * HW;
  const size_t o = (size_t)bk * HW + qt * 1024;
  const int ry0 = qt * 16;
  for (int i = t; i < 24 * 72; i += 256) {
    int ty = i / 72, tx = i - ty * 72;
    int y = ry0 - 4 + ty, xx = tx - 4;
    float v = 0.f;
    if ((unsigned)y < 64u && (unsigned)xx < 64u) v = src[y * 64 + xx] * sc;
    lt[i] = v;
  }
  __syncthreads();
  // pools + identity sum + stats (atomic per-(b,k))
  {
    float s1 = 0.f, q1 = 0.f, s2 = 0.f, q2 = 0.f, s3 = 0.f;
    for (int i = t; i < 1024; i += 256) {
      int lr = i >> 6, col = i & 63;
      int y = ry0 + lr;
      const float* ctr = lt + (lr + 4) * 72 + (col + 4);
      int dy0 = (y > 0) ? -1 : 0, dy1 = (y < 63) ? 1 : 0;
      int dx0 = (col > 0) ? -1 : 0, dx1 = (col < 63) ? 1 : 0;
      float mxv = -INFINITY, sm = 0.f;
      for (int dy = dy0; dy <= dy1; dy++)
        for (int dx = dx0; dx <= dx1; dx++) { float v = ctr[dy * 72 + dx]; mxv = fmaxf(mxv, v); sm += v; }
      float avv = sm / (float)((dy1 - dy0 + 1) * (dx1 - dx0 + 1));
      R[o + i] = mxv; R[IMG + o + i] = avv;
      s1 += mxv; q1 += mxv * mxv; s2 += avv; q2 += avv * avv; s3 += ctr[0];
    }
    s1 = wave_sum(s1); q1 = wave_sum(q1); s2 = wave_sum(s2); q2 = wave_sum(q2); s3 = wave_sum(s3);
    int w = t >> 6;
    if ((t & 63) == 0) { red[w] = s1; red[4 + w] = q1; red[8 + w] = s2; red[12 + w] = q2; red[16 + w] = s3; }
    __syncthreads();
    if (t == 0) {
      atomicAdd(&S[512 + bk],   red[0] + red[1] + red[2] + red[3]);
      atomicAdd(&SQ[512 + bk],  red[4] + red[5] + red[6] + red[7]);
      atomicAdd(&S[1024 + bk],  red[8] + red[9] + red[10] + red[11]);
      atomicAdd(&SQ[1024 + bk], red[12] + red[13] + red[14] + red[15]);
      atomicAdd(&S[1536 + bk],  red[16] + red[17] + red[18] + red[19]);
    }
  }
  // dil3 (K3, dil2)
  {
    float w[9];
#pragma unroll
    for (int i = 0; i < 9; i++) w[i] = d3dw[k * 9 + i];
    for (int i = t; i < 1024; i += 256) {
      int lr = i >> 6, col = i & 63;
      const float* ctr = lt + (lr + 4) * 72 + (col + 4);
      float acc = 0.f;
#pragma unroll
      for (int a = 0; a < 3; a++)
#pragma unroll
        for (int q = 0; q < 3; q++)
          acc = fmaf(w[a * 3 + q], fmaxf(ctr[(2 * a - 2) * 72 + (2 * q - 2)], 0.f), acc);
      scr[0 * IMG + o + i] = acc;
    }
  }
  // dil5 (K5, dil2)
  {
    float w[25];
#pragma unroll
    for (int i = 0; i < 25; i++) w[i] = d5dw[k * 25 + i];
    for (int i = t; i < 1024; i += 256) {
      int lr = i >> 6, col = i & 63;
      const float* ctr = lt + (lr + 4) * 72 + (col + 4);
      float acc = 0.f;
#pragma unroll
      for (int a = 0; a < 5; a++)
#pragma unroll
        for (int q = 0; q < 5; q++)
          acc = fmaf(w[a * 5 + q], fmaxf(ctr[(2 * a - 4) * 72 + (2 * q - 4)], 0.f), acc);
      scr[1 * IMG + o + i] = acc;
    }
  }
  // sep3 stage-1 dw
  {
    float w[9];
#pragma unroll
    for (int i = 0; i < 9; i++) w[i] = s3dw1[k * 9 + i];
    for (int i = t; i < 1024; i += 256) {
      int lr = i >> 6, col = i & 63;
      const float* ctr = lt + (lr + 4) * 72 + (col + 4);
      float acc = 0.f;
#pragma unroll
      for (int a = 0; a < 3; a++)
#pragma unroll
        for (int q = 0; q < 3; q++)
          acc = fmaf(w[a * 3 + q], fmaxf(ctr[(a - 1) * 72 + (q - 1)], 0.f), acc);
      scr[2 * IMG + o + i] = acc;
    }
  }
  // sep5 stage-1 dw
  {
    float w[25];
#pragma unroll
    for (int i = 0; i < 25; i++) w[i] = s5dw1[k * 25 + i];
    for (int i = t; i < 1024; i += 256) {
      int lr = i >> 6, col = i & 63;
      const float* ctr = lt + (lr + 4) * 72 + (col + 4);
      float acc = 0.f;
#pragma unroll
      for (int a = 0; a < 5; a++)
#pragma unroll
        for (int q = 0; q < 5; q++)
          acc = fmaf(w[a * 5 + q], fmaxf(ctr[(a - 2) * 72 + (q - 2)], 0.f), acc);
      scr[3 * IMG + o + i] = acc;
    }
  }
}

// ---- pointwise 16x16 helper: 4 px/thread via float4, stats amortized ----
__device__ __forceinline__ void pw4(const float* __restrict__ in, const float* __restrict__ w16,
                                    float* __restrict__ out, float* __restrict__ sacc,
                                    float* __restrict__ qacc, int perB, int b, int q4,
                                    float* wsh, float* redS, float* redQ) {
  int t = threadIdx.x;
  wsh[t] = w16[t];
  size_t base = (size_t)b * 16 * HW + q4 * 1024 + t * 4;
  float4 sv[16];
#pragma unroll
  for (int i = 0; i < 16; i++) sv[i] = *(const float4*)(in + base + (size_t)i * HW);
  __syncthreads();
  int wv = t >> 6, lane = t & 63;
#pragma unroll
  for (int cc = 0; cc < 16; cc++) {
    float4 o; o.x = 0.f; o.y = 0.f; o.z = 0.f; o.w = 0.f;
#pragma unroll
    for (int i = 0; i < 16; i++) {
      float w = wsh[cc * 16 + i];
      o.x = fmaf(w, sv[i].x, o.x); o.y = fmaf(w, sv[i].y, o.y);
      o.z = fmaf(w, sv[i].z, o.z); o.w = fmaf(w, sv[i].w, o.w);
    }
    *(float4*)(out + base + (size_t)cc * HW) = o;
    float s = (o.x + o.y) + (o.z + o.w);
    float qv = fmaf(o.x, o.x, fmaf(o.y, o.y, fmaf(o.z, o.z, o.w * o.w)));
    s = wave_sum(s); qv = wave_sum(qv);
    if (lane == 0) { redS[cc * 4 + wv] = s; redQ[cc * 4 + wv] = qv; }
  }
  __syncthreads();
  if (t < 16) {
    float s = redS[t * 4] + redS[t * 4 + 1] + redS[t * 4 + 2] + redS[t * 4 + 3];
    float q = redQ[t * 4] + redQ[t * 4 + 1] + redQ[t * 4 + 2] + redQ[t * 4 + 3];
    int sl = perB ? b * 16 + t : t;
    atomicAdd(&sacc[sl], s); atomicAdd(&qacc[sl], q);
  }
}

// ---- Phase B: 4 first pointwise convs, one op per block (512 blocks) ----
__global__ __launch_bounds__(256) void k_fuseB(
    const float* __restrict__ scr,
    const float* __restrict__ d3pw, const float* __restrict__ d5pw,
    const float* __restrict__ s3pw1, const float* __restrict__ s5pw1,
    float* __restrict__ R, float* __restrict__ t3, float* __restrict__ t5,
    float* __restrict__ S, float* __restrict__ SQ, float* __restrict__ U) {
  __shared__ float wsh[256], redS[64], redQ[64];
  int blk = blockIdx.x;
  int op = blk >> 7, rem = blk & 127;
  int b = rem >> 2, q4 = rem & 3;
  switch (op) {
    case 0: pw4(scr + 0 * IMG, d3pw,  R + 4 * IMG, S + 6 * 512, SQ + 6 * 512, 1, b, q4, wsh, redS, redQ); break;
    case 1: pw4(scr + 1 * IMG, d5pw,  R + 5 * IMG, S + 7 * 512, SQ + 7 * 512, 1, b, q4, wsh, redS, redQ); break;
    case 2: pw4(scr + 2 * IMG, s3pw1, t3, U + 0,  U + 16, 0, b, q4, wsh, redS, redQ); break;
    case 3: pw4(scr + 3 * IMG, s5pw1, t5, U + 32, U + 48, 0, b, q4, wsh, redS, redQ); break;
  }
}

// ---- Phase C: second dw convs with lazy-bn, one (op,b,k,quarter) per block ----
template<int KK>
__device__ __forceinline__ void dw_q(const float* __restrict__ src, const float* __restrict__ w,
                                     float* __restrict__ dst, float* lt, float mu, float rs, int qt) {
  constexpr int P = KK / 2, TW = 64 + 2 * P, ROWS = 16 + 2 * P;
  float wr[KK * KK];
#pragma unroll
  for (int i = 0; i < KK * KK; i++) wr[i] = w[i];
  const int t = threadIdx.x;
  const int ry0 = qt * 16;
  for (int i = t; i < ROWS * TW; i += 256) {
    int ty = i / TW, tx = i - ty * TW;
    int y = ry0 - P + ty, xx = tx - P;
    float v = 0.f;
    if ((unsigned)y < 64u && (unsigned)xx < 64u) {
      v = src[y * 64 + xx];
      v = (v - mu) * rs;
      v = fmaxf(v, 0.f);
    }
    lt[i] = v;
  }
  __syncthreads();
  for (int i = t; i < 1024; i += 256) {
    int lr = i >> 6, col = i & 63;
    const float* t0 = lt + lr * TW + col;
    float acc = 0.f;
#pragma unroll
    for (int a = 0; a < KK; a++)
#pragma unroll
      for (int q = 0; q < KK; q++)
        acc = fmaf(wr[a * KK + q], t0[a * TW + q], acc);
    dst[qt * 1024 + i] = acc;
  }
}

__global__ __launch_bounds__(256) void k_fuseC(
    const float* __restrict__ t3, const float* __restrict__ t5,
    const float* __restrict__ s3dw2, const float* __restrict__ s5dw2,
    float* __restrict__ scr, const float* __restrict__ U) {
  __shared__ float lt[20 * 68];
  int blk = blockIdx.x;                  // 4096 = 2 ops x 512 bk x 4 quarters
  int op = blk >> 11, rem = blk & 2047;
  int bk = rem >> 2, qt = rem & 3, k = bk & 15;
  size_t o = (size_t)bk * HW;
  if (op == 0) {
    float mu = U[k] * (1.f / (float)BHW);
    float var = U[16 + k] * (1.f / (float)BHW) - mu * mu;
    dw_q<3>(t3 + o, s3dw2 + k * 9, scr + 0 * IMG + o, lt, mu, rsqrtf(var + 1e-5f), qt);
  } else {
    float mu = U[32 + k] * (1.f / (float)BHW);
    float var = U[48 + k] * (1.f / (float)BHW) - mu * mu;
    dw_q<5>(t5 + o, s5dw2 + k * 25, scr + 1 * IMG + o, lt, mu, rsqrtf(var + 1e-5f), qt);
  }
}

// ---- Phase D: both final pointwise convs (256 blocks) ----
__global__ __launch_bounds__(256) void k_fuseD(
    const float* __restrict__ scr,
    const float* __restrict__ s3pw2, const float* __restrict__ s5pw2,
    float* __restrict__ R, float* __restrict__ S, float* __restrict__ SQ) {
  __shared__ float wsh[256], redS[64], redQ[64];
  int blk = blockIdx.x;
  int op = blk >> 7, rem = blk & 127;
  int b = rem >> 2, q4 = rem & 3;
  if (op == 0) pw4(scr + 0 * IMG, s3pw2, R + 2 * IMG, S + 4 * 512, SQ + 4 * 512, 1, b, q4, wsh, redS, redQ);
  else         pw4(scr + 1 * IMG, s5pw2, R + 3 * IMG, S + 5 * 512, SQ + 5 * 512, 1, b, q4, wsh, redS, redQ);
}

// ---- attention MLP + per-(b,k) accumulation coefficients ----
__global__ __launch_bounds__(128) void k_att(const float* __restrict__ S, const float* __restrict__ SQ,
                                             const float* __restrict__ w1, const float* __restrict__ w2,
                                             float* __restrict__ y, float* __restrict__ aco,
                                             float* __restrict__ bia) {
  int b = blockIdx.x, t = threadIdx.x;
  __shared__ float ym[128], h[16], msh[8][16], rssh[8][16], ysh[128];
  int op = t >> 4, k = t & 15;
  bool isbn = (op == 1 || op == 2 || op >= 4);
  float m = 0.f, rsc = 0.f;
  {
    float ss = 0.f, qq = 0.f;
    for (int bb = 0; bb < B; bb++) { ss += S[op * 512 + bb * 16 + k]; qq += SQ[op * 512 + bb * 16 + k]; }
    if (isbn) {
      m = ss * (1.f / (float)BHW);
      float var = qq * (1.f / (float)BHW) - m * m;
      rsc = rsqrtf(var + 1e-5f);
    }
  }
  msh[op][k] = m; rssh[op][k] = rsc;
  float sm = S[op * 512 + b * 16 + k] * (1.f / 4096.f);
  float yme = (op == 0) ? 0.f : ((op == 3) ? sm : (sm - m) * rsc);
  ym[t] = yme;
  __syncthreads();
  if (t < 16) {
    const float* wr = w1 + (size_t)t * 128;
    float acc = 0.f;
    for (int c = 0; c < 128; c++) acc = fmaf(wr[c], ym[c], acc);
    h[t] = fmaxf(acc, 0.f);
  }
  __syncthreads();
  {
    const float* wr = w2 + (size_t)t * 16;
    float acc = 0.f;
    for (int j = 0; j < 16; j++) acc = fmaf(wr[j], h[j], acc);
    float yy = 1.f / (1.f + expf(-acc));
    ysh[t] = yy; y[b * 128 + t] = yy;
  }
  __syncthreads();
  if (t < 16) {
    float bias = 0.f;
    for (int o2 = 1; o2 < 8; o2++) {
      float yv = ysh[o2 * 16 + t];
      float a;
      if (o2 == 3) a = yv;
      else { a = yv * rssh[o2][t]; bias -= yv * rssh[o2][t] * msh[o2][t]; }
      aco[(b * 16 + t) * 8 + o2] = a;
    }
    bia[b * 16 + t] = bias;
  }
}

// ---- final fused write: fully vectorized; identity folded into x coefficient ----
__global__ __launch_bounds__(256) void k_final(const float* __restrict__ x, const float* __restrict__ num,
                                               const int* __restrict__ selmap,
                                               const float* __restrict__ rbuf, const float* __restrict__ aco,
                                               const float* __restrict__ bia, const float* __restrict__ ybuf,
                                               float* __restrict__ out, float* __restrict__ out8) {
  __shared__ float sh[256];
  int bc = blockIdx.x;
  if (bc == B * C) {
    int t = threadIdx.x, op = t >> 5, lane = t & 31;
    float acc = 0.f;
    for (int i = lane; i < 512; i += 32) { int bb = i >> 4, kk = i & 15; acc += ybuf[bb * 128 + op * 16 + kk]; }
    sh[t] = acc;
    __syncthreads();
    if (lane == 0) {
      float s = 0.f;
      for (int i = 0; i < 32; i++) s += sh[op * 32 + i];
      out8[op] = s;
    }
    return;
  }
  int b = bc >> 8;
  int k = selmap[bc & 255];
  const float4* xs = (const float4*)(x + (size_t)bc * HW);
  float4* od = (float4*)(out + (size_t)bc * HW);
  if (k < 0) {
    float sc = 1.f + num[bc];
    for (int i = threadIdx.x; i < 1024; i += 256) {
      float4 v = xs[i];
      v.x *= sc; v.y *= sc; v.z *= sc; v.w *= sc;
      od[i] = v;
    }
  } else {
    int bk = b * 16 + k;
    float scn = num[bc];                 // idx[k] == own channel: identity = x*scn, folded into xc
    const float4* r0 = (const float4*)(rbuf + ((size_t)0 * 512 + bk) * HW);
    const float4* r1 = (const float4*)(rbuf + ((size_t)1 * 512 + bk) * HW);
    const float4* r2 = (const float4*)(rbuf + ((size_t)2 * 512 + bk) * HW);
    const float4* r3 = (const float4*)(rbuf + ((size_t)3 * 512 + bk) * HW);
    const float4* r4 = (const float4*)(rbuf + ((size_t)4 * 512 + bk) * HW);
    const float4* r5 = (const float4*)(rbuf + ((size_t)5 * 512 + bk) * HW);
    float a1 = aco[bk * 8 + 1], a2 = aco[bk * 8 + 2];
    float a4 = aco[bk * 8 + 4], a5 = aco[bk * 8 + 5], a6 = aco[bk * 8 + 6], a7 = aco[bk * 8 + 7];
    float xc = 1.f + aco[bk * 8 + 3] * scn;
    float bias = bia[bk];
    for (int i = threadIdx.x; i < 1024; i += 256) {
      float4 xv = xs[i];
      float4 v0 = r0[i], v1 = r1[i], v2 = r2[i], v3 = r3[i], v4 = r4[i], v5 = r5[i];
      float4 o;
      o.x = xv.x * xc + bias + a1 * v0.x + a2 * v1.x + a4 * v2.x + a5 * v3.x + a6 * v4.x + a7 * v5.x;
      o.y = xv.y * xc + bias + a1 * v0.y + a2 * v1.y + a4 * v2.y + a5 * v3.y + a6 * v4.y + a7 * v5.y;
      o.z = xv.z * xc + bias + a1 * v0.z + a2 * v1.z + a4 * v2.z + a5 * v3.z + a6 * v4.z + a7 * v5.z;
      o.w = xv.w * xc + bias + a1 * v0.w + a2 * v1.w + a4 * v2.w + a5 * v3.w + a6 * v4.w + a7 * v5.w;
      od[i] = o;
    }
  }
}

extern "C" void kernel_launch(void* const* d_in, const int* in_sizes, int n_in,
                              void* d_out, int out_size, void* d_ws, size_t ws_size,
                              hipStream_t stream) {
  const float* x      = (const float*)d_in[0];
  const float* ca_w1  = (const float*)d_in[1];
  const float* ca_w2  = (const float*)d_in[2];
  const float* s3_dw1 = (const float*)d_in[3];
  const float* s3_pw1 = (const float*)d_in[4];
  const float* s3_dw2 = (const float*)d_in[5];
  const float* s3_pw2 = (const float*)d_in[6];
  const float* s5_dw1 = (const float*)d_in[7];
  const float* s5_pw1 = (const float*)d_in[8];
  const float* s5_dw2 = (const float*)d_in[9];
  const float* s5_pw2 = (const float*)d_in[10];
  const float* d3_dw  = (const float*)d_in[11];
  const float* d3_pw  = (const float*)d_in[12];
  const float* d5_dw  = (const float*)d_in[13];
  const float* d5_pw  = (const float*)d_in[14];
  const float* at_w1  = (const float*)d_in[15];
  const float* at_w2  = (const float*)d_in[16];

  float* ws = (float*)d_ws;
  float* S = ws + OFF_S;  float* SQ = ws + OFF_SQ;  float* U = ws + OFF_U;
  unsigned* cnt = (unsigned*)(ws + OFF_CNT);
  float* mx = ws + OFF_MX; float* av = ws + OFF_AV; float* num = ws + OFF_NUM;
  float* ybuf = ws + OFF_Y; float* aco = ws + OFF_ACO; float* bia = ws + OFF_BIAS;
  int* ib = (int*)(ws + OFF_INT);
  int* idx = ib; int* selmap = ib + 16;
  float* R = ws + OFF_R;

  float* outf = (float*)d_out;
  float* scr = outf;             // 4 x IMG scratch inside d_out (dead before k_final)
  float* t3  = outf + 4 * IMG;
  float* t5  = outf + 5 * IMG;
  float* out8 = outf + (size_t)B * C * HW;

  k_stats<<<B * C, 256, 0, stream>>>((const float4*)x, mx, av, ws);
  k_sesel<<<B, 256, 0, stream>>>(mx, av, ca_w1, ca_w2, num, idx, selmap, cnt);
  k_fuseA<<<2048, 256, 0, stream>>>(x, num, idx, d3_dw, d5_dw, s3_dw1, s5_dw1, scr, R, S, SQ);
  k_fuseB<<<512, 256, 0, stream>>>(scr, d3_pw, d5_pw, s3_pw1, s5_pw1, R, t3, t5, S, SQ, U);
  k_fuseC<<<4096, 256, 0, stream>>>(t3, t5, s3_dw2, s5_dw2, scr, U);
  k_fuseD<<<256, 256, 0, stream>>>(scr, s3_pw2, s5_pw2, R, S, SQ);
  k_att<<<B, 128, 0, stream>>>(S, SQ, at_w1, at_w2, ybuf, aco, bia);
  k_final<<<B * C + 1, 256, 0, stream>>>(x, num, selmap, R, aco, bia, ybuf, outf, out8);
}

// Round 12
// 193.066 us; speedup vs baseline: 1.2271x; 1.0468x over previous
//
#include <hip/hip_runtime.h>
#include <math.h>

static constexpr int B = 32, C = 256, HW = 4096, CS = 16;
static constexpr int BHW = B * HW;                 // 131072
static constexpr size_t IMG = (size_t)B * CS * HW; // 2,097,152 floats per branch buffer

// ---------- workspace layout (floats) ----------
static constexpr size_t OFF_S    = 0;        // 8 ops x 512 (b*16+k) per-(b,c) sums
static constexpr size_t OFF_SQ   = 4096;     // 8 ops x 512 sumsq
static constexpr size_t OFF_U    = 8192;     // u3sum[16],u3sq[16],u5sum[16],u5sq[16]
static constexpr size_t OFF_CNT  = 8256;     // uint counter (sesel)
static constexpr size_t ACC_END  = 8260;     // zero region [0, ACC_END) zeroed by k_stats blk0
static constexpr size_t OFF_MX   = 8320;
static constexpr size_t OFF_AV   = OFF_MX + 8192;
static constexpr size_t OFF_NUM  = OFF_AV + 8192;
static constexpr size_t OFF_INT  = OFF_NUM + 8192;    // idx[16], selmap[256] as ints
static constexpr size_t OFF_R    = OFF_INT + 384;     // 6 x IMG floats

__device__ inline float wave_sum(float v) {
  v += __shfl_down(v, 32); v += __shfl_down(v, 16); v += __shfl_down(v, 8);
  v += __shfl_down(v, 4);  v += __shfl_down(v, 2);  v += __shfl_down(v, 1);
  return v;
}
__device__ inline float wave_max(float v) {
  v = fmaxf(v, __shfl_down(v, 32)); v = fmaxf(v, __shfl_down(v, 16));
  v = fmaxf(v, __shfl_down(v, 8));  v = fmaxf(v, __shfl_down(v, 4));
  v = fmaxf(v, __shfl_down(v, 2));  v = fmaxf(v, __shfl_down(v, 1));
  return v;
}

// ---- K1: per-(b,c) max/mean over HxW; block 0 also zeroes the accumulator region ----
__global__ __launch_bounds__(256) void k_stats(const float4* __restrict__ x,
                                               float* __restrict__ mx, float* __restrict__ av,
                                               float* __restrict__ accbase) {
  int bc = blockIdx.x;
  if (bc == 0) for (int i = threadIdx.x; i < (int)ACC_END; i += 256) accbase[i] = 0.f;
  const float4* p = x + (size_t)bc * 1024;
  float mmax = -INFINITY, msum = 0.f;
  for (int i = threadIdx.x; i < 1024; i += 256) {
    float4 v = p[i];
    mmax = fmaxf(mmax, fmaxf(fmaxf(v.x, v.y), fmaxf(v.z, v.w)));
    msum += v.x + v.y + v.z + v.w;
  }
  __shared__ float rs[4], rm[4];
  float s = wave_sum(msum), m = wave_max(mmax);
  int w = threadIdx.x >> 6;
  if ((threadIdx.x & 63) == 0) { rs[w] = s; rm[w] = m; }
  __syncthreads();
  if (threadIdx.x == 0) {
    mx[bc] = fmaxf(fmaxf(rm[0], rm[1]), fmaxf(rm[2], rm[3]));
    av[bc] = (rs[0] + rs[1] + rs[2] + rs[3]) * (1.f / 4096.f);
  }
}

// ---- K2: SE -> num, with last-block tail doing the top-16 select ----
__global__ __launch_bounds__(256) void k_sesel(const float* __restrict__ mx, const float* __restrict__ av,
                                               const float* __restrict__ w1, const float* __restrict__ w2,
                                               float* __restrict__ num,
                                               int* __restrict__ idx, int* __restrict__ selmap,
                                               unsigned* __restrict__ cnt) {
  __shared__ float zs0[256], zs1[256], h0[128], h1[128];
  __shared__ unsigned lastv;
  int b = blockIdx.x, t = threadIdx.x;
  zs0[t] = mx[b * 256 + t]; zs1[t] = av[b * 256 + t];
  __syncthreads();
  if (t < 128) {
    const float* wr = w1 + (size_t)t * 256;
    float am = 0.f, aa = 0.f;
    for (int i = 0; i < 256; i++) { float w = wr[i]; am = fmaf(w, zs0[i], am); aa = fmaf(w, zs1[i], aa); }
    h0[t] = fmaxf(am, 0.f); h1[t] = fmaxf(aa, 0.f);
  }
  __syncthreads();
  {
    const float* wr = w2 + (size_t)t * 128;
    float sm = 0.f, sa = 0.f;
    for (int j = 0; j < 128; j++) { float w = wr[j]; sm = fmaf(w, h0[j], sm); sa = fmaf(w, h1[j], sa); }
    num[b * 256 + t] = 1.f / (1.f + expf(-(sm + sa)));
  }
  __threadfence();
  if (t == 0) lastv = atomicAdd(cnt, 1u);
  __syncthreads();
  if (lastv == 31u) {
    __threadfence();
    float acc = 0.f;
    for (int bb = 0; bb < B; bb++) acc += num[bb * 256 + t];
    zs0[t] = acc; selmap[t] = -1;
    __syncthreads();
    float v = zs0[t];
    int rank = 0;
    for (int c = 0; c < 256; c++) {
      float o = zs0[c];
      rank += (o > v) || (o == v && c < t);
    }
    if (rank < 16) { idx[rank] = t; selmap[t] = rank; }
  }
}

// ---- Phase A: (b,k,quarter). Stage gated channel quarter (24x72, pad 4); write pools
// + stats + identity sum + all four first-stage dw convs. ----
__global__ __launch_bounds__(256) void k_fuseA(
    const float* __restrict__ x, const float* __restrict__ num, const int* __restrict__ idx,
    const float* __restrict__ d3dw, const float* __restrict__ d5dw,
    const float* __restrict__ s3dw1, const float* __restrict__ s5dw1,
    float* __restrict__ scr, float* __restrict__ R,
    float* __restrict__ S, float* __restrict__ SQ) {
  __shared__ float lt[24 * 72];
  __shared__ float red[20];
  const int t = threadIdx.x;
  const int blk = blockIdx.x;            // 2048 = 512 bk x 4 quarters
  const int bk = blk >> 2, qt = blk & 3;
  const int b = bk >> 4, k = bk & 15;
  const int c = idx[k];
  const float sc = num[b * 256 + c];
  const float* src = x + ((size_t)b * 256 + c) * HW;
  const size_t o = (size_t)bk * HW + qt * 1024;
  const int ry0 = qt * 16;
  for (int i = t; i < 24 * 72; i += 256) {
    int ty = i / 72, tx = i - ty * 72;
    int y = ry0 - 4 + ty, xx = tx - 4;
    float v = 0.f;
    if ((unsigned)y < 64u && (unsigned)xx < 64u) v = src[y * 64 + xx] * sc;
    lt[i] = v;
  }
  __syncthreads();
  // pools + identity sum + stats (atomic per-(b,k))
  {
    float s1 = 0.f, q1 = 0.f, s2 = 0.f, q2 = 0.f, s3 = 0.f;
    for (int i = t; i < 1024; i += 256) {
      int lr = i >> 6, col = i & 63;
      int y = ry0 + lr;
      const float* ctr = lt + (lr + 4) * 72 + (col + 4);
      int dy0 = (y > 0) ? -1 : 0, dy1 = (y < 63) ? 1 : 0;
      int dx0 = (col > 0) ? -1 : 0, dx1 = (col < 63) ? 1 : 0;
      float mxv = -INFINITY, sm = 0.f;
      for (int dy = dy0; dy <= dy1; dy++)
        for (int dx = dx0; dx <= dx1; dx++) { float v = ctr[dy * 72 + dx]; mxv = fmaxf(mxv, v); sm += v; }
      float avv = sm / (float)((dy1 - dy0 + 1) * (dx1 - dx0 + 1));
      R[o + i] = mxv; R[IMG + o + i] = avv;
      s1 += mxv; q1 += mxv * mxv; s2 += avv; q2 += avv * avv; s3 += ctr[0];
    }
    s1 = wave_sum(s1); q1 = wave_sum(q1); s2 = wave_sum(s2); q2 = wave_sum(q2); s3 = wave_sum(s3);
    int w = t >> 6;
    if ((t & 63) == 0) { red[w] = s1; red[4 + w] = q1; red[8 + w] = s2; red[12 + w] = q2; red[16 + w] = s3; }
    __syncthreads();
    if (t == 0) {
      atomicAdd(&S[512 + bk],   red[0] + red[1] + red[2] + red[3]);
      atomicAdd(&SQ[512 + bk],  red[4] + red[5] + red[6] + red[7]);
      atomicAdd(&S[1024 + bk],  red[8] + red[9] + red[10] + red[11]);
      atomicAdd(&SQ[1024 + bk], red[12] + red[13] + red[14] + red[15]);
      atomicAdd(&S[1536 + bk],  red[16] + red[17] + red[18] + red[19]);
    }
  }
  // dil3 (K3, dil2)
  {
    float w[9];
#pragma unroll
    for (int i = 0; i < 9; i++) w[i] = d3dw[k * 9 + i];
    for (int i = t; i < 1024; i += 256) {
      int lr = i >> 6, col = i & 63;
      const float* ctr = lt + (lr + 4) * 72 + (col + 4);
      float acc = 0.f;
#pragma unroll
      for (int a = 0; a < 3; a++)
#pragma unroll
        for (int q = 0; q < 3; q++)
          acc = fmaf(w[a * 3 + q], fmaxf(ctr[(2 * a - 2) * 72 + (2 * q - 2)], 0.f), acc);
      scr[0 * IMG + o + i] = acc;
    }
  }
  // dil5 (K5, dil2)
  {
    float w[25];
#pragma unroll
    for (int i = 0; i < 25; i++) w[i] = d5dw[k * 25 + i];
    for (int i = t; i < 1024; i += 256) {
      int lr = i >> 6, col = i & 63;
      const float* ctr = lt + (lr + 4) * 72 + (col + 4);
      float acc = 0.f;
#pragma unroll
      for (int a = 0; a < 5; a++)
#pragma unroll
        for (int q = 0; q < 5; q++)
          acc = fmaf(w[a * 5 + q], fmaxf(ctr[(2 * a - 4) * 72 + (2 * q - 4)], 0.f), acc);
      scr[1 * IMG + o + i] = acc;
    }
  }
  // sep3 stage-1 dw
  {
    float w[9];
#pragma unroll
    for (int i = 0; i < 9; i++) w[i] = s3dw1[k * 9 + i];
    for (int i = t; i < 1024; i += 256) {
      int lr = i >> 6, col = i & 63;
      const float* ctr = lt + (lr + 4) * 72 + (col + 4);
      float acc = 0.f;
#pragma unroll
      for (int a = 0; a < 3; a++)
#pragma unroll
        for (int q = 0; q < 3; q++)
          acc = fmaf(w[a * 3 + q], fmaxf(ctr[(a - 1) * 72 + (q - 1)], 0.f), acc);
      scr[2 * IMG + o + i] = acc;
    }
  }
  // sep5 stage-1 dw
  {
    float w[25];
#pragma unroll
    for (int i = 0; i < 25; i++) w[i] = s5dw1[k * 25 + i];
    for (int i = t; i < 1024; i += 256) {
      int lr = i >> 6, col = i & 63;
      const float* ctr = lt + (lr + 4) * 72 + (col + 4);
      float acc = 0.f;
#pragma unroll
      for (int a = 0; a < 5; a++)
#pragma unroll
        for (int q = 0; q < 5; q++)
          acc = fmaf(w[a * 5 + q], fmaxf(ctr[(a - 2) * 72 + (q - 2)], 0.f), acc);
      scr[3 * IMG + o + i] = acc;
    }
  }
}

// ---- pointwise 16x16 helper: 4 px/thread via float4, stats amortized ----
__device__ __forceinline__ void pw4(const float* __restrict__ in, const float* __restrict__ w16,
                                    float* __restrict__ out, float* __restrict__ sacc,
                                    float* __restrict__ qacc, int perB, int b, int q4,
                                    float* wsh, float* redS, float* redQ) {
  int t = threadIdx.x;
  wsh[t] = w16[t];
  size_t base = (size_t)b * 16 * HW + q4 * 1024 + t * 4;
  float4 sv[16];
#pragma unroll
  for (int i = 0; i < 16; i++) sv[i] = *(const float4*)(in + base + (size_t)i * HW);
  __syncthreads();
  int wv = t >> 6, lane = t & 63;
#pragma unroll
  for (int cc = 0; cc < 16; cc++) {
    float4 o; o.x = 0.f; o.y = 0.f; o.z = 0.f; o.w = 0.f;
#pragma unroll
    for (int i = 0; i < 16; i++) {
      float w = wsh[cc * 16 + i];
      o.x = fmaf(w, sv[i].x, o.x); o.y = fmaf(w, sv[i].y, o.y);
      o.z = fmaf(w, sv[i].z, o.z); o.w = fmaf(w, sv[i].w, o.w);
    }
    *(float4*)(out + base + (size_t)cc * HW) = o;
    float s = (o.x + o.y) + (o.z + o.w);
    float qv = fmaf(o.x, o.x, fmaf(o.y, o.y, fmaf(o.z, o.z, o.w * o.w)));
    s = wave_sum(s); qv = wave_sum(qv);
    if (lane == 0) { redS[cc * 4 + wv] = s; redQ[cc * 4 + wv] = qv; }
  }
  __syncthreads();
  if (t < 16) {
    float s = redS[t * 4] + redS[t * 4 + 1] + redS[t * 4 + 2] + redS[t * 4 + 3];
    float q = redQ[t * 4] + redQ[t * 4 + 1] + redQ[t * 4 + 2] + redQ[t * 4 + 3];
    int sl = perB ? b * 16 + t : t;
    atomicAdd(&sacc[sl], s); atomicAdd(&qacc[sl], q);
  }
}

// ---- Phase B: 4 first pointwise convs, one op per block (512 blocks) ----
__global__ __launch_bounds__(256) void k_fuseB(
    const float* __restrict__ scr,
    const float* __restrict__ d3pw, const float* __restrict__ d5pw,
    const float* __restrict__ s3pw1, const float* __restrict__ s5pw1,
    float* __restrict__ R, float* __restrict__ t3, float* __restrict__ t5,
    float* __restrict__ S, float* __restrict__ SQ, float* __restrict__ U) {
  __shared__ float wsh[256], redS[64], redQ[64];
  int blk = blockIdx.x;
  int op = blk >> 7, rem = blk & 127;
  int b = rem >> 2, q4 = rem & 3;
  switch (op) {
    case 0: pw4(scr + 0 * IMG, d3pw,  R + 4 * IMG, S + 6 * 512, SQ + 6 * 512, 1, b, q4, wsh, redS, redQ); break;
    case 1: pw4(scr + 1 * IMG, d5pw,  R + 5 * IMG, S + 7 * 512, SQ + 7 * 512, 1, b, q4, wsh, redS, redQ); break;
    case 2: pw4(scr + 2 * IMG, s3pw1, t3, U + 0,  U + 16, 0, b, q4, wsh, redS, redQ); break;
    case 3: pw4(scr + 3 * IMG, s5pw1, t5, U + 32, U + 48, 0, b, q4, wsh, redS, redQ); break;
  }
}

// ---- Phase C: second dw convs with lazy-bn, one (op,b,k,quarter) per block ----
template<int KK>
__device__ __forceinline__ void dw_q(const float* __restrict__ src, const float* __restrict__ w,
                                     float* __restrict__ dst, float* lt, float mu, float rs, int qt) {
  constexpr int P = KK / 2, TW = 64 + 2 * P, ROWS = 16 + 2 * P;
  float wr[KK * KK];
#pragma unroll
  for (int i = 0; i < KK * KK; i++) wr[i] = w[i];
  const int t = threadIdx.x;
  const int ry0 = qt * 16;
  for (int i = t; i < ROWS * TW; i += 256) {
    int ty = i / TW, tx = i - ty * TW;
    int y = ry0 - P + ty, xx = tx - P;
    float v = 0.f;
    if ((unsigned)y < 64u && (unsigned)xx < 64u) {
      v = src[y * 64 + xx];
      v = (v - mu) * rs;
      v = fmaxf(v, 0.f);
    }
    lt[i] = v;
  }
  __syncthreads();
  for (int i = t; i < 1024; i += 256) {
    int lr = i >> 6, col = i & 63;
    const float* t0 = lt + lr * TW + col;
    float acc = 0.f;
#pragma unroll
    for (int a = 0; a < KK; a++)
#pragma unroll
      for (int q = 0; q < KK; q++)
        acc = fmaf(wr[a * KK + q], t0[a * TW + q], acc);
    dst[qt * 1024 + i] = acc;
  }
}

__global__ __launch_bounds__(256) void k_fuseC(
    const float* __restrict__ t3, const float* __restrict__ t5,
    const float* __restrict__ s3dw2, const float* __restrict__ s5dw2,
    float* __restrict__ scr, const float* __restrict__ U) {
  __shared__ float lt[20 * 68];
  int blk = blockIdx.x;                  // 4096 = 2 ops x 512 bk x 4 quarters
  int op = blk >> 11, rem = blk & 2047;
  int bk = rem >> 2, qt = rem & 3, k = bk & 15;
  size_t o = (size_t)bk * HW;
  if (op == 0) {
    float mu = U[k] * (1.f / (float)BHW);
    float var = U[16 + k] * (1.f / (float)BHW) - mu * mu;
    dw_q<3>(t3 + o, s3dw2 + k * 9, scr + 0 * IMG + o, lt, mu, rsqrtf(var + 1e-5f), qt);
  } else {
    float mu = U[32 + k] * (1.f / (float)BHW);
    float var = U[48 + k] * (1.f / (float)BHW) - mu * mu;
    dw_q<5>(t5 + o, s5dw2 + k * 25, scr + 1 * IMG + o, lt, mu, rsqrtf(var + 1e-5f), qt);
  }
}

// ---- Phase D: both final pointwise convs (256 blocks) ----
__global__ __launch_bounds__(256) void k_fuseD(
    const float* __restrict__ scr,
    const float* __restrict__ s3pw2, const float* __restrict__ s5pw2,
    float* __restrict__ R, float* __restrict__ S, float* __restrict__ SQ) {
  __shared__ float wsh[256], redS[64], redQ[64];
  int blk = blockIdx.x;
  int op = blk >> 7, rem = blk & 127;
  int b = rem >> 2, q4 = rem & 3;
  if (op == 0) pw4(scr + 0 * IMG, s3pw2, R + 2 * IMG, S + 4 * 512, SQ + 4 * 512, 1, b, q4, wsh, redS, redQ);
  else         pw4(scr + 1 * IMG, s5pw2, R + 3 * IMG, S + 5 * 512, SQ + 5 * 512, 1, b, q4, wsh, redS, redQ);
}

// ---- compute msh/rssh (per-(op,k) bn params) into LDS; threads 0..127 ----
__device__ __forceinline__ void att_bnstats(const float* __restrict__ S, const float* __restrict__ SQ,
                                            float* msh, float* rssh) {
  int t = threadIdx.x;
  if (t < 128) {
    int op2 = t >> 4, kk = t & 15;
    bool isbn = (op2 == 1 || op2 == 2 || op2 >= 4);
    float ss = 0.f, qq = 0.f;
    for (int bb = 0; bb < B; bb++) { ss += S[op2 * 512 + bb * 16 + kk]; qq += SQ[op2 * 512 + bb * 16 + kk]; }
    float m = 0.f, rsc = 0.f;
    if (isbn) { m = ss * (1.f / (float)BHW); float var = qq * (1.f / (float)BHW) - m * m; rsc = rsqrtf(var + 1e-5f); }
    msh[t] = m; rssh[t] = rsc;
  }
}

// ---- final fused write; att MLP computed inline (no k_att dispatch) ----
// block 0: op_attention over all batches; blocks 1..B*C: one channel each.
__global__ __launch_bounds__(256) void k_final(const float* __restrict__ x, const float* __restrict__ num,
                                               const int* __restrict__ selmap,
                                               const float* __restrict__ rbuf,
                                               const float* __restrict__ S, const float* __restrict__ SQ,
                                               const float* __restrict__ w1, const float* __restrict__ w2,
                                               float* __restrict__ out, float* __restrict__ out8) {
  __shared__ float msh[128], rssh[128];
  const int bid = blockIdx.x, t = threadIdx.x;

  if (bid == 0) {
    // ---- op_attention: y for all 32 batches (2 halves of 16), fixed-order reduce ----
    __shared__ float ym2[16][129], hh2[16][17], sh[256];
    att_bnstats(S, SQ, msh, rssh);
    __syncthreads();
    float myacc = 0.f;                       // this thread always contributes to op (t&127)>>4
    for (int half = 0; half < 2; half++) {
      int b0 = half * 16;
      for (int e = t; e < 2048; e += 256) {
        int bb = e >> 7, cc = e & 127, op2 = cc >> 4;
        float sm = S[op2 * 512 + (b0 + bb) * 16 + (cc & 15)] * (1.f / 4096.f);
        ym2[bb][cc] = (op2 == 0) ? 0.f : ((op2 == 3) ? sm : (sm - msh[cc]) * rssh[cc]);
      }
      __syncthreads();
      {
        int bb = t >> 4, u = t & 15;
        const float* wr = w1 + (size_t)u * 128;
        float acc = 0.f;
        for (int c2 = 0; c2 < 128; c2++) acc = fmaf(wr[c2], ym2[bb][c2], acc);
        hh2[bb][u] = fmaxf(acc, 0.f);
      }
      __syncthreads();
      for (int e = t; e < 2048; e += 256) {
        int bb = e >> 7, oo = e & 127;
        const float* wr = w2 + (size_t)oo * 16;
        float acc = 0.f;
        for (int j = 0; j < 16; j++) acc = fmaf(wr[j], hh2[bb][j], acc);
        myacc += 1.f / (1.f + expf(-acc));
      }
      __syncthreads();
    }
    sh[t] = myacc;
    __syncthreads();
    if (t < 8) {
      float s = 0.f;
      for (int i = 0; i < 16; i++) s += sh[t * 16 + i];
      for (int i = 0; i < 16; i++) s += sh[128 + t * 16 + i];
      out8[t] = s;
    }
    return;
  }

  const int bc = bid - 1;
  const int b = bc >> 8;
  const int k = selmap[bc & 255];
  const float4* xs = (const float4*)(x + (size_t)bc * HW);
  float4* od = (float4*)(out + (size_t)bc * HW);

  if (k < 0) {
    float sc = 1.f + num[bc];
    for (int i = t; i < 1024; i += 256) {
      float4 v = xs[i];
      v.x *= sc; v.y *= sc; v.z *= sc; v.w *= sc;
      od[i] = v;
    }
    return;
  }

  // ---- selected channel: inline att MLP for batch b (bitwise-identical across blocks) ----
  __shared__ float ym[128], hh[16], ysh[128];
  att_bnstats(S, SQ, msh, rssh);
  if (t < 128) {
    int op2 = t >> 4, kk = t & 15;
    // note: msh/rssh written by this same thread above; LDS visible after sync below
  }
  __syncthreads();
  if (t < 128) {
    int op2 = t >> 4;
    float sm = S[op2 * 512 + b * 16 + (t & 15)] * (1.f / 4096.f);
    ym[t] = (op2 == 0) ? 0.f : ((op2 == 3) ? sm : (sm - msh[t]) * rssh[t]);
  }
  __syncthreads();
  if (t < 16) {
    const float* wr = w1 + (size_t)t * 128;
    float acc = 0.f;
    for (int c2 = 0; c2 < 128; c2++) acc = fmaf(wr[c2], ym[c2], acc);
    hh[t] = fmaxf(acc, 0.f);
  }
  __syncthreads();
  if (t < 128) {
    const float* wr = w2 + (size_t)t * 16;
    float acc = 0.f;
    for (int j = 0; j < 16; j++) acc = fmaf(wr[j], hh[j], acc);
    ysh[t] = 1.f / (1.f + expf(-acc));
  }
  __syncthreads();

  const int bk = b * 16 + k;
  float scn = num[bc];                 // idx[k] == own channel: identity = x*scn, folded into xc
  float a1 = ysh[16 + k] * rssh[16 + k];
  float a2 = ysh[32 + k] * rssh[32 + k];
  float a3 = ysh[48 + k];
  float a4 = ysh[64 + k] * rssh[64 + k];
  float a5 = ysh[80 + k] * rssh[80 + k];
  float a6 = ysh[96 + k] * rssh[96 + k];
  float a7 = ysh[112 + k] * rssh[112 + k];
  float bias = -(a1 * msh[16 + k] + a2 * msh[32 + k] + a4 * msh[64 + k]
               + a5 * msh[80 + k] + a6 * msh[96 + k] + a7 * msh[112 + k]);
  float xc = 1.f + a3 * scn;

  const float4* r0 = (const float4*)(rbuf + ((size_t)0 * 512 + bk) * HW);
  const float4* r1 = (const float4*)(rbuf + ((size_t)1 * 512 + bk) * HW);
  const float4* r2 = (const float4*)(rbuf + ((size_t)2 * 512 + bk) * HW);
  const float4* r3 = (const float4*)(rbuf + ((size_t)3 * 512 + bk) * HW);
  const float4* r4 = (const float4*)(rbuf + ((size_t)4 * 512 + bk) * HW);
  const float4* r5 = (const float4*)(rbuf + ((size_t)5 * 512 + bk) * HW);
  for (int i = t; i < 1024; i += 256) {
    float4 xv = xs[i];
    float4 v0 = r0[i], v1 = r1[i], v2 = r2[i], v3 = r3[i], v4 = r4[i], v5 = r5[i];
    float4 o;
    o.x = xv.x * xc + bias + a1 * v0.x + a2 * v1.x + a4 * v2.x + a5 * v3.x + a6 * v4.x + a7 * v5.x;
    o.y = xv.y * xc + bias + a1 * v0.y + a2 * v1.y + a4 * v2.y + a5 * v3.y + a6 * v4.y + a7 * v5.y;
    o.z = xv.z * xc + bias + a1 * v0.z + a2 * v1.z + a4 * v2.z + a5 * v3.z + a6 * v4.z + a7 * v5.z;
    o.w = xv.w * xc + bias + a1 * v0.w + a2 * v1.w + a4 * v2.w + a5 * v3.w + a6 * v4.w + a7 * v5.w;
    od[i] = o;
  }
}

extern "C" void kernel_launch(void* const* d_in, const int* in_sizes, int n_in,
                              void* d_out, int out_size, void* d_ws, size_t ws_size,
                              hipStream_t stream) {
  const float* x      = (const float*)d_in[0];
  const float* ca_w1  = (const float*)d_in[1];
  const float* ca_w2  = (const float*)d_in[2];
  const float* s3_dw1 = (const float*)d_in[3];
  const float* s3_pw1 = (const float*)d_in[4];
  const float* s3_dw2 = (const float*)d_in[5];
  const float* s3_pw2 = (const float*)d_in[6];
  const float* s5_dw1 = (const float*)d_in[7];
  const float* s5_pw1 = (const float*)d_in[8];
  const float* s5_dw2 = (const float*)d_in[9];
  const float* s5_pw2 = (const float*)d_in[10];
  const float* d3_dw  = (const float*)d_in[11];
  const float* d3_pw  = (const float*)d_in[12];
  const float* d5_dw  = (const float*)d_in[13];
  const float* d5_pw  = (const float*)d_in[14];
  const float* at_w1  = (const float*)d_in[15];
  const float* at_w2  = (const float*)d_in[16];

  float* ws = (float*)d_ws;
  float* S = ws + OFF_S;  float* SQ = ws + OFF_SQ;  float* U = ws + OFF_U;
  unsigned* cnt = (unsigned*)(ws + OFF_CNT);
  float* mx = ws + OFF_MX; float* av = ws + OFF_AV; float* num = ws + OFF_NUM;
  int* ib = (int*)(ws + OFF_INT);
  int* idx = ib; int* selmap = ib + 16;
  float* R = ws + OFF_R;

  float* outf = (float*)d_out;
  float* scr = outf;             // 4 x IMG scratch inside d_out (dead before k_final)
  float* t3  = outf + 4 * IMG;
  float* t5  = outf + 5 * IMG;
  float* out8 = outf + (size_t)B * C * HW;

  k_stats<<<B * C, 256, 0, stream>>>((const float4*)x, mx, av, ws);
  k_sesel<<<B, 256, 0, stream>>>(mx, av, ca_w1, ca_w2, num, idx, selmap, cnt);
  k_fuseA<<<2048, 256, 0, stream>>>(x, num, idx, d3_dw, d5_dw, s3_dw1, s5_dw1, scr, R, S, SQ);
  k_fuseB<<<512, 256, 0, stream>>>(scr, d3_pw, d5_pw, s3_pw1, s5_pw1, R, t3, t5, S, SQ, U);
  k_fuseC<<<4096, 256, 0, stream>>>(t3, t5, s3_dw2, s5_dw2, scr, U);
  k_fuseD<<<256, 256, 0, stream>>>(scr, s3_pw2, s5_pw2, R, S, SQ);
  k_final<<<B * C + 1, 256, 0, stream>>>(x, num, selmap, R, S, SQ, at_w1, at_w2, outf, out8);
}

// Round 13
// 185.543 us; speedup vs baseline: 1.2769x; 1.0405x over previous
//
#include <hip/hip_runtime.h>
#include <math.h>

static constexpr int B = 32, C = 256, HW = 4096, CS = 16;
static constexpr int BHW = B * HW;                 // 131072
static constexpr size_t IMG = (size_t)B * CS * HW; // 2,097,152 floats per branch buffer

// ---------- workspace layout (floats) ----------
static constexpr size_t OFF_S    = 0;        // 8 ops x 512 (b*16+k) per-(b,c) sums
static constexpr size_t OFF_SQ   = 4096;     // 8 ops x 512 sumsq
static constexpr size_t OFF_U    = 8192;     // u3sum[16],u3sq[16],u5sum[16],u5sq[16]
static constexpr size_t OFF_CNT  = 8256;     // uint counter (sesel)
static constexpr size_t ACC_END  = 8260;     // zero region [0, ACC_END) zeroed by k_stats blk0
static constexpr size_t OFF_MX   = 8320;
static constexpr size_t OFF_AV   = OFF_MX + 8192;
static constexpr size_t OFF_NUM  = OFF_AV + 8192;
static constexpr size_t OFF_INT  = OFF_NUM + 8192;    // idx[16], selmap[256] as ints
static constexpr size_t OFF_R    = OFF_INT + 384;     // 6 x IMG floats

__device__ inline float wave_sum(float v) {
  v += __shfl_down(v, 32); v += __shfl_down(v, 16); v += __shfl_down(v, 8);
  v += __shfl_down(v, 4);  v += __shfl_down(v, 2);  v += __shfl_down(v, 1);
  return v;
}
__device__ inline float wave_max(float v) {
  v = fmaxf(v, __shfl_down(v, 32)); v = fmaxf(v, __shfl_down(v, 16));
  v = fmaxf(v, __shfl_down(v, 8));  v = fmaxf(v, __shfl_down(v, 4));
  v = fmaxf(v, __shfl_down(v, 2));  v = fmaxf(v, __shfl_down(v, 1));
  return v;
}

// ---- K1: per-(b,c) max/mean over HxW; block 0 also zeroes the accumulator region ----
__global__ __launch_bounds__(256) void k_stats(const float4* __restrict__ x,
                                               float* __restrict__ mx, float* __restrict__ av,
                                               float* __restrict__ accbase) {
  int bc = blockIdx.x;
  if (bc == 0) for (int i = threadIdx.x; i < (int)ACC_END; i += 256) accbase[i] = 0.f;
  const float4* p = x + (size_t)bc * 1024;
  float mmax = -INFINITY, msum = 0.f;
  for (int i = threadIdx.x; i < 1024; i += 256) {
    float4 v = p[i];
    mmax = fmaxf(mmax, fmaxf(fmaxf(v.x, v.y), fmaxf(v.z, v.w)));
    msum += v.x + v.y + v.z + v.w;
  }
  __shared__ float rs[4], rm[4];
  float s = wave_sum(msum), m = wave_max(mmax);
  int w = threadIdx.x >> 6;
  if ((threadIdx.x & 63) == 0) { rs[w] = s; rm[w] = m; }
  __syncthreads();
  if (threadIdx.x == 0) {
    mx[bc] = fmaxf(fmaxf(rm[0], rm[1]), fmaxf(rm[2], rm[3]));
    av[bc] = (rs[0] + rs[1] + rs[2] + rs[3]) * (1.f / 4096.f);
  }
}

// ---- K2: SE -> num, with last-block tail doing the top-16 select ----
__global__ __launch_bounds__(256) void k_sesel(const float* __restrict__ mx, const float* __restrict__ av,
                                               const float* __restrict__ w1, const float* __restrict__ w2,
                                               float* __restrict__ num,
                                               int* __restrict__ idx, int* __restrict__ selmap,
                                               unsigned* __restrict__ cnt) {
  __shared__ float zs0[256], zs1[256], h0[128], h1[128];
  __shared__ unsigned lastv;
  int b = blockIdx.x, t = threadIdx.x;
  zs0[t] = mx[b * 256 + t]; zs1[t] = av[b * 256 + t];
  __syncthreads();
  if (t < 128) {
    const float* wr = w1 + (size_t)t * 256;
    float am = 0.f, aa = 0.f;
    for (int i = 0; i < 256; i++) { float w = wr[i]; am = fmaf(w, zs0[i], am); aa = fmaf(w, zs1[i], aa); }
    h0[t] = fmaxf(am, 0.f); h1[t] = fmaxf(aa, 0.f);
  }
  __syncthreads();
  {
    const float* wr = w2 + (size_t)t * 128;
    float sm = 0.f, sa = 0.f;
    for (int j = 0; j < 128; j++) { float w = wr[j]; sm = fmaf(w, h0[j], sm); sa = fmaf(w, h1[j], sa); }
    num[b * 256 + t] = 1.f / (1.f + expf(-(sm + sa)));
  }
  __threadfence();
  if (t == 0) lastv = atomicAdd(cnt, 1u);
  __syncthreads();
  if (lastv == 31u) {
    __threadfence();
    float acc = 0.f;
    for (int bb = 0; bb < B; bb++) acc += num[bb * 256 + t];
    zs0[t] = acc; selmap[t] = -1;
    __syncthreads();
    float v = zs0[t];
    int rank = 0;
    for (int c = 0; c < 256; c++) {
      float o = zs0[c];
      rank += (o > v) || (o == v && c < t);
    }
    if (rank < 16) { idx[rank] = t; selmap[t] = rank; }
  }
}

// ---- Phase A: (b,k,quarter). Stage gated channel quarter (24x72, pad 4); write pools
// + stats + identity sum + all four first-stage dw convs. ----
__global__ __launch_bounds__(256) void k_fuseA(
    const float* __restrict__ x, const float* __restrict__ num, const int* __restrict__ idx,
    const float* __restrict__ d3dw, const float* __restrict__ d5dw,
    const float* __restrict__ s3dw1, const float* __restrict__ s5dw1,
    float* __restrict__ scr, float* __restrict__ R,
    float* __restrict__ S, float* __restrict__ SQ) {
  __shared__ float lt[24 * 72];
  __shared__ float red[20];
  const int t = threadIdx.x;
  const int blk = blockIdx.x;            // 2048 = 512 bk x 4 quarters
  const int bk = blk >> 2, qt = blk & 3;
  const int b = bk >> 4, k = bk & 15;
  const int c = idx[k];
  const float sc = num[b * 256 + c];
  const float* src = x + ((size_t)b * 256 + c) * HW;
  const size_t o = (size_t)bk * HW + qt * 1024;
  const int ry0 = qt * 16;
  for (int i = t; i < 24 * 72; i += 256) {
    int ty = i / 72, tx = i - ty * 72;
    int y = ry0 - 4 + ty, xx = tx - 4;
    float v = 0.f;
    if ((unsigned)y < 64u && (unsigned)xx < 64u) v = src[y * 64 + xx] * sc;
    lt[i] = v;
  }
  __syncthreads();
  // pools + identity sum + stats (atomic per-(b,k))
  {
    float s1 = 0.f, q1 = 0.f, s2 = 0.f, q2 = 0.f, s3 = 0.f;
    for (int i = t; i < 1024; i += 256) {
      int lr = i >> 6, col = i & 63;
      int y = ry0 + lr;
      const float* ctr = lt + (lr + 4) * 72 + (col + 4);
      int dy0 = (y > 0) ? -1 : 0, dy1 = (y < 63) ? 1 : 0;
      int dx0 = (col > 0) ? -1 : 0, dx1 = (col < 63) ? 1 : 0;
      float mxv = -INFINITY, sm = 0.f;
      for (int dy = dy0; dy <= dy1; dy++)
        for (int dx = dx0; dx <= dx1; dx++) { float v = ctr[dy * 72 + dx]; mxv = fmaxf(mxv, v); sm += v; }
      float avv = sm / (float)((dy1 - dy0 + 1) * (dx1 - dx0 + 1));
      R[o + i] = mxv; R[IMG + o + i] = avv;
      s1 += mxv; q1 += mxv * mxv; s2 += avv; q2 += avv * avv; s3 += ctr[0];
    }
    s1 = wave_sum(s1); q1 = wave_sum(q1); s2 = wave_sum(s2); q2 = wave_sum(q2); s3 = wave_sum(s3);
    int w = t >> 6;
    if ((t & 63) == 0) { red[w] = s1; red[4 + w] = q1; red[8 + w] = s2; red[12 + w] = q2; red[16 + w] = s3; }
    __syncthreads();
    if (t == 0) {
      atomicAdd(&S[512 + bk],   red[0] + red[1] + red[2] + red[3]);
      atomicAdd(&SQ[512 + bk],  red[4] + red[5] + red[6] + red[7]);
      atomicAdd(&S[1024 + bk],  red[8] + red[9] + red[10] + red[11]);
      atomicAdd(&SQ[1024 + bk], red[12] + red[13] + red[14] + red[15]);
      atomicAdd(&S[1536 + bk],  red[16] + red[17] + red[18] + red[19]);
    }
  }
  // dil3 (K3, dil2)
  {
    float w[9];
#pragma unroll
    for (int i = 0; i < 9; i++) w[i] = d3dw[k * 9 + i];
    for (int i = t; i < 1024; i += 256) {
      int lr = i >> 6, col = i & 63;
      const float* ctr = lt + (lr + 4) * 72 + (col + 4);
      float acc = 0.f;
#pragma unroll
      for (int a = 0; a < 3; a++)
#pragma unroll
        for (int q = 0; q < 3; q++)
          acc = fmaf(w[a * 3 + q], fmaxf(ctr[(2 * a - 2) * 72 + (2 * q - 2)], 0.f), acc);
      scr[0 * IMG + o + i] = acc;
    }
  }
  // dil5 (K5, dil2)
  {
    float w[25];
#pragma unroll
    for (int i = 0; i < 25; i++) w[i] = d5dw[k * 25 + i];
    for (int i = t; i < 1024; i += 256) {
      int lr = i >> 6, col = i & 63;
      const float* ctr = lt + (lr + 4) * 72 + (col + 4);
      float acc = 0.f;
#pragma unroll
      for (int a = 0; a < 5; a++)
#pragma unroll
        for (int q = 0; q < 5; q++)
          acc = fmaf(w[a * 5 + q], fmaxf(ctr[(2 * a - 4) * 72 + (2 * q - 4)], 0.f), acc);
      scr[1 * IMG + o + i] = acc;
    }
  }
  // sep3 stage-1 dw
  {
    float w[9];
#pragma unroll
    for (int i = 0; i < 9; i++) w[i] = s3dw1[k * 9 + i];
    for (int i = t; i < 1024; i += 256) {
      int lr = i >> 6, col = i & 63;
      const float* ctr = lt + (lr + 4) * 72 + (col + 4);
      float acc = 0.f;
#pragma unroll
      for (int a = 0; a < 3; a++)
#pragma unroll
        for (int q = 0; q < 3; q++)
          acc = fmaf(w[a * 3 + q], fmaxf(ctr[(a - 1) * 72 + (q - 1)], 0.f), acc);
      scr[2 * IMG + o + i] = acc;
    }
  }
  // sep5 stage-1 dw
  {
    float w[25];
#pragma unroll
    for (int i = 0; i < 25; i++) w[i] = s5dw1[k * 25 + i];
    for (int i = t; i < 1024; i += 256) {
      int lr = i >> 6, col = i & 63;
      const float* ctr = lt + (lr + 4) * 72 + (col + 4);
      float acc = 0.f;
#pragma unroll
      for (int a = 0; a < 5; a++)
#pragma unroll
        for (int q = 0; q < 5; q++)
          acc = fmaf(w[a * 5 + q], fmaxf(ctr[(a - 2) * 72 + (q - 2)], 0.f), acc);
      scr[3 * IMG + o + i] = acc;
    }
  }
}

// ---- pointwise 16x16 helper: 2 px/thread via float2 (512-px chunk), stats amortized ----
__device__ __forceinline__ void pw2(const float* __restrict__ in, const float* __restrict__ w16,
                                    float* __restrict__ out, float* __restrict__ sacc,
                                    float* __restrict__ qacc, int perB, int b, int q8,
                                    float* wsh, float* redS, float* redQ) {
  int t = threadIdx.x;
  wsh[t] = w16[t];
  size_t base = (size_t)b * 16 * HW + q8 * 512 + t * 2;
  float2 sv[16];
#pragma unroll
  for (int i = 0; i < 16; i++) sv[i] = *(const float2*)(in + base + (size_t)i * HW);
  __syncthreads();
  int wv = t >> 6, lane = t & 63;
#pragma unroll
  for (int cc = 0; cc < 16; cc++) {
    float2 o; o.x = 0.f; o.y = 0.f;
#pragma unroll
    for (int i = 0; i < 16; i++) {
      float w = wsh[cc * 16 + i];
      o.x = fmaf(w, sv[i].x, o.x); o.y = fmaf(w, sv[i].y, o.y);
    }
    *(float2*)(out + base + (size_t)cc * HW) = o;
    float s = o.x + o.y;
    float qv = fmaf(o.x, o.x, o.y * o.y);
    s = wave_sum(s); qv = wave_sum(qv);
    if (lane == 0) { redS[cc * 4 + wv] = s; redQ[cc * 4 + wv] = qv; }
  }
  __syncthreads();
  if (t < 16) {
    float s = redS[t * 4] + redS[t * 4 + 1] + redS[t * 4 + 2] + redS[t * 4 + 3];
    float q = redQ[t * 4] + redQ[t * 4 + 1] + redQ[t * 4 + 2] + redQ[t * 4 + 3];
    int sl = perB ? b * 16 + t : t;
    atomicAdd(&sacc[sl], s); atomicAdd(&qacc[sl], q);
  }
}

// ---- Phase B: 4 first pointwise convs, one (op,b,q8) per block (1024 blocks) ----
__global__ __launch_bounds__(256) void k_fuseB(
    const float* __restrict__ scr,
    const float* __restrict__ d3pw, const float* __restrict__ d5pw,
    const float* __restrict__ s3pw1, const float* __restrict__ s5pw1,
    float* __restrict__ R, float* __restrict__ t3, float* __restrict__ t5,
    float* __restrict__ S, float* __restrict__ SQ, float* __restrict__ U) {
  __shared__ float wsh[256], redS[64], redQ[64];
  int blk = blockIdx.x;
  int op = blk >> 8, rem = blk & 255;
  int b = rem >> 3, q8 = rem & 7;
  switch (op) {
    case 0: pw2(scr + 0 * IMG, d3pw,  R + 4 * IMG, S + 6 * 512, SQ + 6 * 512, 1, b, q8, wsh, redS, redQ); break;
    case 1: pw2(scr + 1 * IMG, d5pw,  R + 5 * IMG, S + 7 * 512, SQ + 7 * 512, 1, b, q8, wsh, redS, redQ); break;
    case 2: pw2(scr + 2 * IMG, s3pw1, t3, U + 0,  U + 16, 0, b, q8, wsh, redS, redQ); break;
    case 3: pw2(scr + 3 * IMG, s5pw1, t5, U + 32, U + 48, 0, b, q8, wsh, redS, redQ); break;
  }
}

// ---- Phase C: second dw convs with lazy-bn, one (op,b,k,quarter) per block ----
template<int KK>
__device__ __forceinline__ void dw_q(const float* __restrict__ src, const float* __restrict__ w,
                                     float* __restrict__ dst, float* lt, float mu, float rs, int qt) {
  constexpr int P = KK / 2, TW = 64 + 2 * P, ROWS = 16 + 2 * P;
  float wr[KK * KK];
#pragma unroll
  for (int i = 0; i < KK * KK; i++) wr[i] = w[i];
  const int t = threadIdx.x;
  const int ry0 = qt * 16;
  for (int i = t; i < ROWS * TW; i += 256) {
    int ty = i / TW, tx = i - ty * TW;
    int y = ry0 - P + ty, xx = tx - P;
    float v = 0.f;
    if ((unsigned)y < 64u && (unsigned)xx < 64u) {
      v = src[y * 64 + xx];
      v = (v - mu) * rs;
      v = fmaxf(v, 0.f);
    }
    lt[i] = v;
  }
  __syncthreads();
  for (int i = t; i < 1024; i += 256) {
    int lr = i >> 6, col = i & 63;
    const float* t0 = lt + lr * TW + col;
    float acc = 0.f;
#pragma unroll
    for (int a = 0; a < KK; a++)
#pragma unroll
      for (int q = 0; q < KK; q++)
        acc = fmaf(wr[a * KK + q], t0[a * TW + q], acc);
    dst[qt * 1024 + i] = acc;
  }
}

__global__ __launch_bounds__(256) void k_fuseC(
    const float* __restrict__ t3, const float* __restrict__ t5,
    const float* __restrict__ s3dw2, const float* __restrict__ s5dw2,
    float* __restrict__ scr, const float* __restrict__ U) {
  __shared__ float lt[20 * 68];
  int blk = blockIdx.x;                  // 4096 = 2 ops x 512 bk x 4 quarters
  int op = blk >> 11, rem = blk & 2047;
  int bk = rem >> 2, qt = rem & 3, k = bk & 15;
  size_t o = (size_t)bk * HW;
  if (op == 0) {
    float mu = U[k] * (1.f / (float)BHW);
    float var = U[16 + k] * (1.f / (float)BHW) - mu * mu;
    dw_q<3>(t3 + o, s3dw2 + k * 9, scr + 0 * IMG + o, lt, mu, rsqrtf(var + 1e-5f), qt);
  } else {
    float mu = U[32 + k] * (1.f / (float)BHW);
    float var = U[48 + k] * (1.f / (float)BHW) - mu * mu;
    dw_q<5>(t5 + o, s5dw2 + k * 25, scr + 1 * IMG + o, lt, mu, rsqrtf(var + 1e-5f), qt);
  }
}

// ---- Phase D: both final pointwise convs, one (op,b,q8) per block (512 blocks) ----
__global__ __launch_bounds__(256) void k_fuseD(
    const float* __restrict__ scr,
    const float* __restrict__ s3pw2, const float* __restrict__ s5pw2,
    float* __restrict__ R, float* __restrict__ S, float* __restrict__ SQ) {
  __shared__ float wsh[256], redS[64], redQ[64];
  int blk = blockIdx.x;
  int op = blk >> 8, rem = blk & 255;
  int b = rem >> 3, q8 = rem & 7;
  if (op == 0) pw2(scr + 0 * IMG, s3pw2, R + 2 * IMG, S + 4 * 512, SQ + 4 * 512, 1, b, q8, wsh, redS, redQ);
  else         pw2(scr + 1 * IMG, s5pw2, R + 3 * IMG, S + 5 * 512, SQ + 5 * 512, 1, b, q8, wsh, redS, redQ);
}

// ---- compute msh/rssh (per-(op,k) bn params) into LDS; threads 0..127 ----
__device__ __forceinline__ void att_bnstats(const float* __restrict__ S, const float* __restrict__ SQ,
                                            float* msh, float* rssh) {
  int t = threadIdx.x;
  if (t < 128) {
    int op2 = t >> 4, kk = t & 15;
    bool isbn = (op2 == 1 || op2 == 2 || op2 >= 4);
    float ss = 0.f, qq = 0.f;
    for (int bb = 0; bb < B; bb++) { ss += S[op2 * 512 + bb * 16 + kk]; qq += SQ[op2 * 512 + bb * 16 + kk]; }
    float m = 0.f, rsc = 0.f;
    if (isbn) { m = ss * (1.f / (float)BHW); float var = qq * (1.f / (float)BHW) - m * m; rsc = rsqrtf(var + 1e-5f); }
    msh[t] = m; rssh[t] = rsc;
  }
}

// ---- final fused write; att MLP computed inline (no k_att dispatch) ----
// block 0: op_attention over all batches; blocks 1..B*C: one channel each.
__global__ __launch_bounds__(256) void k_final(const float* __restrict__ x, const float* __restrict__ num,
                                               const int* __restrict__ selmap,
                                               const float* __restrict__ rbuf,
                                               const float* __restrict__ S, const float* __restrict__ SQ,
                                               const float* __restrict__ w1, const float* __restrict__ w2,
                                               float* __restrict__ out, float* __restrict__ out8) {
  __shared__ float msh[128], rssh[128];
  const int bid = blockIdx.x, t = threadIdx.x;

  if (bid == 0) {
    // ---- op_attention: y for all 32 batches (2 halves of 16), fixed-order reduce ----
    __shared__ float ym2[16][129], hh2[16][17], sh[256];
    att_bnstats(S, SQ, msh, rssh);
    __syncthreads();
    float myacc = 0.f;
    for (int half = 0; half < 2; half++) {
      int b0 = half * 16;
      for (int e = t; e < 2048; e += 256) {
        int bb = e >> 7, cc = e & 127, op2 = cc >> 4;
        float sm = S[op2 * 512 + (b0 + bb) * 16 + (cc & 15)] * (1.f / 4096.f);
        ym2[bb][cc] = (op2 == 0) ? 0.f : ((op2 == 3) ? sm : (sm - msh[cc]) * rssh[cc]);
      }
      __syncthreads();
      {
        int bb = t >> 4, u = t & 15;
        const float* wr = w1 + (size_t)u * 128;
        float acc = 0.f;
        for (int c2 = 0; c2 < 128; c2++) acc = fmaf(wr[c2], ym2[bb][c2], acc);
        hh2[bb][u] = fmaxf(acc, 0.f);
      }
      __syncthreads();
      for (int e = t; e < 2048; e += 256) {
        int bb = e >> 7, oo = e & 127;
        const float* wr = w2 + (size_t)oo * 16;
        float acc = 0.f;
        for (int j = 0; j < 16; j++) acc = fmaf(wr[j], hh2[bb][j], acc);
        myacc += 1.f / (1.f + expf(-acc));
      }
      __syncthreads();
    }
    sh[t] = myacc;
    __syncthreads();
    if (t < 8) {
      float s = 0.f;
      for (int i = 0; i < 16; i++) s += sh[t * 16 + i];
      for (int i = 0; i < 16; i++) s += sh[128 + t * 16 + i];
      out8[t] = s;
    }
    return;
  }

  const int bc = bid - 1;
  const int b = bc >> 8;
  const int k = selmap[bc & 255];
  const float4* xs = (const float4*)(x + (size_t)bc * HW);
  float4* od = (float4*)(out + (size_t)bc * HW);

  if (k < 0) {
    float sc = 1.f + num[bc];
    for (int i = t; i < 1024; i += 256) {
      float4 v = xs[i];
      v.x *= sc; v.y *= sc; v.z *= sc; v.w *= sc;
      od[i] = v;
    }
    return;
  }

  // ---- selected channel: inline att MLP for batch b (bitwise-identical across blocks) ----
  __shared__ float ym[128], hh[16], ysh[128];
  att_bnstats(S, SQ, msh, rssh);
  __syncthreads();
  if (t < 128) {
    int op2 = t >> 4;
    float sm = S[op2 * 512 + b * 16 + (t & 15)] * (1.f / 4096.f);
    ym[t] = (op2 == 0) ? 0.f : ((op2 == 3) ? sm : (sm - msh[t]) * rssh[t]);
  }
  __syncthreads();
  if (t < 16) {
    const float* wr = w1 + (size_t)t * 128;
    float acc = 0.f;
    for (int c2 = 0; c2 < 128; c2++) acc = fmaf(wr[c2], ym[c2], acc);
    hh[t] = fmaxf(acc, 0.f);
  }
  __syncthreads();
  if (t < 128) {
    const float* wr = w2 + (size_t)t * 16;
    float acc = 0.f;
    for (int j = 0; j < 16; j++) acc = fmaf(wr[j], hh[j], acc);
    ysh[t] = 1.f / (1.f + expf(-acc));
  }
  __syncthreads();

  const int bk = b * 16 + k;
  float scn = num[bc];                 // idx[k] == own channel: identity = x*scn, folded into xc
  float a1 = ysh[16 + k] * rssh[16 + k];
  float a2 = ysh[32 + k] * rssh[32 + k];
  float a3 = ysh[48 + k];
  float a4 = ysh[64 + k] * rssh[64 + k];
  float a5 = ysh[80 + k] * rssh[80 + k];
  float a6 = ysh[96 + k] * rssh[96 + k];
  float a7 = ysh[112 + k] * rssh[112 + k];
  float bias = -(a1 * msh[16 + k] + a2 * msh[32 + k] + a4 * msh[64 + k]
               + a5 * msh[80 + k] + a6 * msh[96 + k] + a7 * msh[112 + k]);
  float xc = 1.f + a3 * scn;

  const float4* r0 = (const float4*)(rbuf + ((size_t)0 * 512 + bk) * HW);
  const float4* r1 = (const float4*)(rbuf + ((size_t)1 * 512 + bk) * HW);
  const float4* r2 = (const float4*)(rbuf + ((size_t)2 * 512 + bk) * HW);
  const float4* r3 = (const float4*)(rbuf + ((size_t)3 * 512 + bk) * HW);
  const float4* r4 = (const float4*)(rbuf + ((size_t)4 * 512 + bk) * HW);
  const float4* r5 = (const float4*)(rbuf + ((size_t)5 * 512 + bk) * HW);
  for (int i = t; i < 1024; i += 256) {
    float4 xv = xs[i];
    float4 v0 = r0[i], v1 = r1[i], v2 = r2[i], v3 = r3[i], v4 = r4[i], v5 = r5[i];
    float4 o;
    o.x = xv.x * xc + bias + a1 * v0.x + a2 * v1.x + a4 * v2.x + a5 * v3.x + a6 * v4.x + a7 * v5.x;
    o.y = xv.y * xc + bias + a1 * v0.y + a2 * v1.y + a4 * v2.y + a5 * v3.y + a6 * v4.y + a7 * v5.y;
    o.z = xv.z * xc + bias + a1 * v0.z + a2 * v1.z + a4 * v2.z + a5 * v3.z + a6 * v4.z + a7 * v5.z;
    o.w = xv.w * xc + bias + a1 * v0.w + a2 * v1.w + a4 * v2.w + a5 * v3.w + a6 * v4.w + a7 * v5.w;
    od[i] = o;
  }
}

extern "C" void kernel_launch(void* const* d_in, const int* in_sizes, int n_in,
                              void* d_out, int out_size, void* d_ws, size_t ws_size,
                              hipStream_t stream) {
  const float* x      = (const float*)d_in[0];
  const float* ca_w1  = (const float*)d_in[1];
  const float* ca_w2  = (const float*)d_in[2];
  const float* s3_dw1 = (const float*)d_in[3];
  const float* s3_pw1 = (const float*)d_in[4];
  const float* s3_dw2 = (const float*)d_in[5];
  const float* s3_pw2 = (const float*)d_in[6];
  const float* s5_dw1 = (const float*)d_in[7];
  const float* s5_pw1 = (const float*)d_in[8];
  const float* s5_dw2 = (const float*)d_in[9];
  const float* s5_pw2 = (const float*)d_in[10];
  const float* d3_dw  = (const float*)d_in[11];
  const float* d3_pw  = (const float*)d_in[12];
  const float* d5_dw  = (const float*)d_in[13];
  const float* d5_pw  = (const float*)d_in[14];
  const float* at_w1  = (const float*)d_in[15];
  const float* at_w2  = (const float*)d_in[16];

  float* ws = (float*)d_ws;
  float* S = ws + OFF_S;  float* SQ = ws + OFF_SQ;  float* U = ws + OFF_U;
  unsigned* cnt = (unsigned*)(ws + OFF_CNT);
  float* mx = ws + OFF_MX; float* av = ws + OFF_AV; float* num = ws + OFF_NUM;
  int* ib = (int*)(ws + OFF_INT);
  int* idx = ib; int* selmap = ib + 16;
  float* R = ws + OFF_R;

  float* outf = (float*)d_out;
  float* scr = outf;             // 4 x IMG scratch inside d_out (dead before k_final)
  float* t3  = outf + 4 * IMG;
  float* t5  = outf + 5 * IMG;
  float* out8 = outf + (size_t)B * C * HW;

  k_stats<<<B * C, 256, 0, stream>>>((const float4*)x, mx, av, ws);
  k_sesel<<<B, 256, 0, stream>>>(mx, av, ca_w1, ca_w2, num, idx, selmap, cnt);
  k_fuseA<<<2048, 256, 0, stream>>>(x, num, idx, d3_dw, d5_dw, s3_dw1, s5_dw1, scr, R, S, SQ);
  k_fuseB<<<1024, 256, 0, stream>>>(scr, d3_pw, d5_pw, s3_pw1, s5_pw1, R, t3, t5, S, SQ, U);
  k_fuseC<<<4096, 256, 0, stream>>>(t3, t5, s3_dw2, s5_dw2, scr, U);
  k_fuseD<<<512, 256, 0, stream>>>(scr, s3_pw2, s5_pw2, R, S, SQ);
  k_final<<<B * C + 1, 256, 0, stream>>>(x, num, selmap, R, S, SQ, at_w1, at_w2, outf, out8);
}